// Round 5
// baseline (268.125 us; speedup 1.0000x reference)
//
#include <hip/hip_runtime.h>

// ---------- types ----------
typedef __attribute__((ext_vector_type(8))) _Float16 h8;
typedef __attribute__((ext_vector_type(4))) _Float16 h4;
typedef __attribute__((ext_vector_type(4))) float f32x4;

__device__ __forceinline__ _Float16 f2h(float f) { return (_Float16)f; }
__device__ __forceinline__ float h2f(_Float16 h) { return (float)h; }

// swizzled element index into feat LDS tile [px][128] (XOR of i bits 3..5 with px&7)
__device__ __forceinline__ int fswz(int p, int i) { return p * 128 + (i ^ ((p & 7) << 3)); }

// ---------- ws layout (bytes) ----------
// sta is TILE-MAJOR: [b][row 0..95][xtile 0..2][ch 0..63][px 0..31] h16
// tile = 64ch*32px = 2048 h16 = 4096 B, fully written by one k_sta WG.
#define WS_STA   0u          // _Float16 [1152 tiles][2048]      4718592 B
#define WS_GSI   4718592u    // int   [4][4]  {dx,dy,sdx,sdy}
#define WS_GSF   4718656u    // float [4][4]  {wx1,wy1,swx1,swy1}
#define WS_WCPX  4718720u    // float [4][8][64]
#define WS_WEPX  4726912u    // float [4][64][8]
#define WS_FUSB  4735104u    // _Float16 [4][4][64][8]  (fusion B fragments)
#define WS_KCB   4751488u    // float [1600] permuted bias
#define WS_KCW   4757888u    // _Float16 [1600][64] permuted kc_w

// =====================================================================
// k_prep: permute+convert kc_w -> f16 (j' = w*400 + t*16 + cl), permuted
// bias, and fusion-weight B-fragments.
// =====================================================================
__global__ __launch_bounds__(256) void k_prep(
    const float* __restrict__ kc_w, const float* __restrict__ kc_b,
    const float* __restrict__ fusw,
    _Float16* __restrict__ kcw, _Float16* __restrict__ fusB,
    float* __restrict__ kcbp)
{
  int e = blockIdx.x * 256 + threadIdx.x;
  if (e < 25600) {
    int jp = e >> 4, i0 = (e & 15) << 2;
    int w = jp / 400, rem = jp % 400;
    int t = rem >> 4, cl = rem & 15;
    int j = (w * 16 + cl) * 25 + t;           // original row: channel-major c*25+t
    const float4* src = (const float4*)(kc_w + j * 64 + i0);
    float4 v = *src;
    h4 ov;
    ov[0] = f2h(v.x); ov[1] = f2h(v.y); ov[2] = f2h(v.z); ov[3] = f2h(v.w);
    *(h4*)(kcw + jp * 64 + i0) = ov;
  }
  if (e < 8192) {
    // fusB[Nt][ks][lane][j] = fus_w[(Nt*16 + (l&15))*128 + (l>>4)*8 + 32*ks + j]
    int Nt = e >> 11, ks = (e >> 9) & 3, l = (e >> 3) & 63, j = e & 7;
    fusB[e] = f2h(fusw[(Nt * 16 + (l & 15)) * 128 + (l >> 4) * 8 + 32 * ks + j]);
  }
  if (e < 1600) {
    int w = e / 400, rem = e % 400, t = rem >> 4, cl = rem & 15;
    kcbp[e] = kc_b[(w * 16 + cl) * 25 + t];
  }
}

// =====================================================================
// k_embed: the 4 parity variants of the coordinate embedding ->
// grid-sample tables + combined MoE weights.
// =====================================================================
__global__ __launch_bounds__(256) void k_embed(
    const float* __restrict__ b1w, const float* __restrict__ b1b,
    const float* __restrict__ b2w, const float* __restrict__ b2b,
    const float* __restrict__ rw,  const float* __restrict__ rb,
    const float* __restrict__ ow,  const float* __restrict__ ob,
    const float* __restrict__ sow, const float* __restrict__ sob,
    const float* __restrict__ wc,  const float* __restrict__ we,
    int* __restrict__ gs_i, float* __restrict__ gs_f,
    float* __restrict__ wcpx, float* __restrict__ wepx)
{
  __shared__ float l_w2[4096];
  __shared__ float l_h1[4][64];
  __shared__ float l_h2[4][64];
  __shared__ float l_sm[4][8];
  int tid = threadIdx.x;
  for (int e = tid; e < 4096; e += 256) l_w2[e] = b2w[e];
  int g = tid >> 6, o = tid & 63;
  float py = (g >> 1) ? 1.f : 0.f;
  float pxx = (g & 1) ? 1.f : 0.f;
  float chh = (py + 0.5f) * 0.5f;
  float coh = chh - floorf(chh + 0.001f) - 0.5f;
  float cww = (pxx + 0.5f) * 0.5f;
  float cow = cww - floorf(cww + 0.001f) - 0.5f;
  float z = b1b[o] + b1w[o * 4 + 0] * 0.5f + b1w[o * 4 + 1] * 0.5f
          + b1w[o * 4 + 2] * coh + b1w[o * 4 + 3] * cow;
  l_h1[g][o] = fmaxf(z, 0.f);
  __syncthreads();
  float z2 = b2b[o];
  #pragma unroll 8
  for (int i = 0; i < 64; i++) z2 = fmaf(l_w2[o * 64 + i], l_h1[g][i], z2);
  l_h2[g][o] = fmaxf(z2, 0.f);
  __syncthreads();
  if (o < 8) {
    const float* wp; float bias;
    if (o < 4)      { wp = rw  + o * 64;       bias = rb[o]; }
    else if (o < 6) { wp = ow  + (o - 4) * 64; bias = ob[o - 4]; }
    else            { wp = sow + (o - 6) * 64; bias = sob[o - 6]; }
    float acc = bias;
    for (int i = 0; i < 64; i++) acc = fmaf(wp[i], l_h2[g][i], acc);
    if (o < 4) acc = 1.f / (1.f + expf(-acc));
    l_sm[g][o] = acc;
  }
  __syncthreads();
  if (o == 0) {
    float qbx = (g & 1) ? 0.25f : -0.25f;
    float qby = (g >> 1) ? 0.25f : -0.25f;
    float qx  = qbx + l_sm[g][4]; float fx  = floorf(qx);
    float qy  = qby + l_sm[g][5]; float fy  = floorf(qy);
    float qsx = qbx + l_sm[g][6]; float fsx = floorf(qsx);
    float qsy = qby + l_sm[g][7]; float fsy = floorf(qsy);
    gs_i[g * 4 + 0] = (int)fx;  gs_f[g * 4 + 0] = qx - fx;
    gs_i[g * 4 + 1] = (int)fy;  gs_f[g * 4 + 1] = qy - fy;
    gs_i[g * 4 + 2] = (int)fsx; gs_f[g * 4 + 2] = qsx - fsx;
    gs_i[g * 4 + 3] = (int)fsy; gs_f[g * 4 + 3] = qsy - fsy;
  }
  float r0 = l_sm[g][0], r1 = l_sm[g][1], r2 = l_sm[g][2], r3 = l_sm[g][3];
  for (int idx = o; idx < 512; idx += 64) {
    wcpx[g * 512 + idx] = r0 * wc[idx] + r1 * wc[512 + idx] + r2 * wc[1024 + idx] + r3 * wc[1536 + idx];
    wepx[g * 512 + idx] = r0 * we[idx] + r1 * we[512 + idx] + r2 * we[1024 + idx] + r3 * we[1536 + idx];
  }
}

// =====================================================================
// k_sta: fused kernel_warp (f16 MFMA GEMM) + 5x5 spatially-varying conv.
// R5: 512 threads = 8 waves: wave (w = channel group 0..3, half = px
// subtile 0..1). Each wave: 16 ch x 16 px, 25 taps x 2 MFMA, acc in regs.
// Epilogue: direct h4 stores into tile-major sta (WG owns a full 4 KB
// tile -> no partial-line write amplification, no LDS transpose).
// =====================================================================
__global__ __launch_bounds__(512, 8) void k_sta(
    const float* __restrict__ x, const float* __restrict__ st,
    const _Float16* __restrict__ kcw, const float* __restrict__ kcbp,
    _Float16* __restrict__ sta_out)
{
  __shared__ __align__(16) _Float16 x_lds[64 * 5 * 40];   // [c][row 0..4][col 0..35 (+pad)]
  __shared__ __align__(16) _Float16 st_lds[32 * 72];      // [px][ch] (+pad)
  int wg = (blockIdx.x & 7) * 144 + (blockIdx.x >> 3);    // XCD-contiguous chunks
  int b = wg / 288;
  int r1 = wg % 288;
  int hb = r1 / 3, wb = r1 % 3;
  int tid = threadIdx.x, lane = tid & 63;
  int w = (tid >> 6) & 3, half = tid >> 8;                // wave = (w, half)
  // ---- stage x tile (5 rows x 36 cols x 64 ch), float4 interior + scalar edges ----
  for (int e = tid; e < 2560; e += 512) {           // interior: cols 2..33
    int row = e >> 3, v = e & 7;                    // row = c*5+rr
    int rr = row % 5;
    int grow = min(max(hb + rr - 2, 0), 95);
    float4 val = *(const float4*)&x[((b * 64 + (row / 5)) * 96 + grow) * 96 + 32 * wb + v * 4];
    _Float16* dst = &x_lds[row * 40 + 2 + v * 4];
    dst[0] = f2h(val.x); dst[1] = f2h(val.y); dst[2] = f2h(val.z); dst[3] = f2h(val.w);
  }
  for (int e = tid; e < 1280; e += 512) {           // edges: cols 0,1,34,35
    int row = e >> 2, j = e & 3;
    int col = (j < 2) ? j : 32 + j;
    int rr = row % 5;
    int grow = min(max(hb + rr - 2, 0), 95);
    int gcol = min(max(32 * wb + col - 2, 0), 95);
    x_lds[row * 40 + col] = f2h(x[((b * 64 + (row / 5)) * 96 + grow) * 96 + gcol]);
  }
  // ---- stage st tile (64 ch x 32 px) coalesced, transposed to [px][ch] ----
  for (int e = tid; e < 512; e += 512) {
    int c = e >> 3, p0 = (e & 7) * 4;
    float4 v = *(const float4*)&st[((size_t)(b * 64 + c) * 96 + hb) * 96 + 32 * wb + p0];
    st_lds[(p0 + 0) * 72 + c] = f2h(v.x);
    st_lds[(p0 + 1) * 72 + c] = f2h(v.y);
    st_lds[(p0 + 2) * 72 + c] = f2h(v.z);
    st_lds[(p0 + 3) * 72 + c] = f2h(v.w);
  }
  __syncthreads();
  // ---- A fragment from LDS: this wave's 16-px subtile, 2 k-steps ----
  int l15 = lane & 15, lg = lane >> 4;
  h8 afrag[2];
  #pragma unroll
  for (int ks = 0; ks < 2; ks++)
    afrag[ks] = *(const h8*)&st_lds[(half * 16 + l15) * 72 + 32 * ks + lg * 8];
  // ---- main loop: per tap, MFMA kw (stays in regs) -> conv accumulate ----
  float sta_acc[4];
  #pragma unroll
  for (int r = 0; r < 4; r++) sta_acc[r] = 0.f;
  for (int dh = 0; dh < 5; dh++) {
    // 8 contiguous h16 at cols [half*16+lg*4 .. +7] of channel w*16+l15
    const _Float16* xp = &x_lds[((w * 16 + l15) * 5 + dh) * 40 + half * 16 + lg * 4];
    h4 xa0 = *(const h4*)xp;
    h4 xa1 = *(const h4*)(xp + 4);
    #pragma unroll
    for (int dw = 0; dw < 5; dw++) {
      int jbase = w * 400 + (dh * 5 + dw) * 16;
      const _Float16* bp = kcw + (jbase + l15) * 64 + lg * 8;
      h8 bf0 = *(const h8*)bp;
      h8 bf1 = *(const h8*)(bp + 32);
      float kb = kcbp[jbase + l15];
      f32x4 acc = {0.f, 0.f, 0.f, 0.f};
      acc = __builtin_amdgcn_mfma_f32_16x16x32_f16(afrag[0], bf0, acc, 0, 0, 0);
      acc = __builtin_amdgcn_mfma_f32_16x16x32_f16(afrag[1], bf1, acc, 0, 0, 0);
      #pragma unroll
      for (int r = 0; r < 4; r++) {
        float kw = acc[r] + kb;
        kw = (kw >= 0.f) ? kw : 0.1f * kw;      // leaky_relu 0.1 (kw stays f32)
        int ci = r + dw;                        // static after unroll
        float xvf = h2f(ci < 4 ? xa0[ci] : xa1[ci - 4]);
        sta_acc[r] = fmaf(kw, xvf, sta_acc[r]);
      }
    }
  }
  // ---- epilogue: direct store into this WG's 4 KB tile (tile-major) ----
  // lane (l15, lg) of wave (w, half): ch = w*16+l15, px = half*16+lg*4+r
  {
    h4 ov;
    #pragma unroll
    for (int r = 0; r < 4; r++) ov[r] = f2h(sta_acc[r]);
    _Float16* tp = sta_out + ((size_t)((b * 96 + hb) * 3 + wb) << 11);
    *(h4*)(tp + (w * 16 + l15) * 32 + half * 16 + lg * 4) = ov;
  }
}

// =====================================================================
// k_main: per 64-pixel HR row chunk: grid samples (parity-table stencils),
// MoE (precombined weights, scalar-load), fusion conv via f16 MFMA.
// R5: sta reads use the tile-major layout.
// =====================================================================
__global__ __launch_bounds__(256) void k_main(
    const float* __restrict__ x, const _Float16* __restrict__ sta,
    const int* __restrict__ gs_i, const float* __restrict__ gs_f,
    const float* __restrict__ wcpx, const float* __restrict__ wepx,
    const _Float16* __restrict__ fusB, const float* __restrict__ fusb,
    float* __restrict__ out)
{
  __shared__ __align__(16) _Float16 feat[64 * 128]; // swizzled [px][0:64 sta_hr | 64:128 fea0->fea]
  __shared__ float t_lds[8][68];
  int wg = (blockIdx.x & 7) * 288 + (blockIdx.x >> 3);  // XCD-contiguous chunks
  int b = wg / 576, r = wg % 576;
  int y = r / 3, xb = r % 3;
  int tid = threadIdx.x, px = tid & 63, fg = tid >> 6;
  int xg = xb * 64 + px;
  int v = ((y & 1) << 1) | (xg & 1);
  int idxo = gs_i[v * 4 + 0], idyo = gs_i[v * 4 + 1], idxs = gs_i[v * 4 + 2], idys = gs_i[v * 4 + 3];
  float wx1 = gs_f[v * 4 + 0], wy1 = gs_f[v * 4 + 1], sx1 = gs_f[v * 4 + 2], sy1 = gs_f[v * 4 + 3];
  int xh = xg >> 1, yh = y >> 1;
  // offset path (fea0 from x)
  int ix0 = xh + idxo, iy0 = yh + idyo;
  float wx0 = 1.f - wx1, wy0 = 1.f - wy1;
  bool vx0 = (unsigned)ix0 < 96u, vx1 = (unsigned)(ix0 + 1) < 96u;
  bool vy0 = (unsigned)iy0 < 96u, vy1 = (unsigned)(iy0 + 1) < 96u;
  int cx0 = min(max(ix0, 0), 95), cx1 = min(max(ix0 + 1, 0), 95);
  int cy0 = min(max(iy0, 0), 95), cy1 = min(max(iy0 + 1, 0), 95);
  float ww00 = (vx0 && vy0) ? wy0 * wx0 : 0.f;
  float ww10 = (vx1 && vy0) ? wy0 * wx1 : 0.f;
  float ww01 = (vx0 && vy1) ? wy1 * wx0 : 0.f;
  float ww11 = (vx1 && vy1) ? wy1 * wx1 : 0.f;
  int a00 = cy0 * 96 + cx0, a10 = cy0 * 96 + cx1, a01 = cy1 * 96 + cx0, a11 = cy1 * 96 + cx1;
  // st_offset path (sta_hr from tile-major sta)
  int jx0 = xh + idxs, jy0 = yh + idys;
  float sx0 = 1.f - sx1, sy0 = 1.f - sy1;
  bool ux0 = (unsigned)jx0 < 96u, ux1 = (unsigned)(jx0 + 1) < 96u;
  bool uy0 = (unsigned)jy0 < 96u, uy1 = (unsigned)(jy0 + 1) < 96u;
  int dx0 = min(max(jx0, 0), 95), dx1 = min(max(jx0 + 1, 0), 95);
  int dy0 = min(max(jy0, 0), 95), dy1 = min(max(jy0 + 1, 0), 95);
  float sw00 = (ux0 && uy0) ? sy0 * sx0 : 0.f;
  float sw10 = (ux1 && uy0) ? sy0 * sx1 : 0.f;
  float sw01 = (ux0 && uy1) ? sy1 * sx0 : 0.f;
  float sw11 = (ux1 && uy1) ? sy1 * sx1 : 0.f;
  // tiled offsets: ((b*96+dy)*3 + dx>>5)*2048 + (dx&31), + ch*32 inside loop
  int s00 = (((b * 96 + dy0) * 3 + (dx0 >> 5)) << 11) + (dx0 & 31);
  int s10 = (((b * 96 + dy0) * 3 + (dx1 >> 5)) << 11) + (dx1 & 31);
  int s01 = (((b * 96 + dy1) * 3 + (dx0 >> 5)) << 11) + (dx0 & 31);
  int s11 = (((b * 96 + dy1) * 3 + (dx1 >> 5)) << 11) + (dx1 & 31);
  // ---- P1: gather sta_hr + fea0, 16 channels per thread-group ----
  h8 stv0, stv1, fev0, fev1;
  #pragma unroll
  for (int k = 0; k < 16; k++) {
    int ch = fg * 16 + k;
    const float* xc = x + (size_t)(b * 64 + ch) * 9216;
    float f0 = ww00 * xc[a00] + ww10 * xc[a10] + ww01 * xc[a01] + ww11 * xc[a11];
    const _Float16* sc = sta + ch * 32;
    float s0 = sw00 * h2f(sc[s00]) + sw10 * h2f(sc[s10]) + sw01 * h2f(sc[s01]) + sw11 * h2f(sc[s11]);
    if (k < 8) { stv0[k] = f2h(s0); fev0[k] = f2h(f0); }
    else       { stv1[k - 8] = f2h(s0); fev1[k - 8] = f2h(f0); }
  }
  *(h8*)&feat[fswz(px, fg * 16)]          = stv0;
  *(h8*)&feat[fswz(px, fg * 16 + 8)]      = stv1;
  *(h8*)&feat[fswz(px, 64 + fg * 16)]     = fev0;
  *(h8*)&feat[fswz(px, 64 + fg * 16 + 8)] = fev1;
  __syncthreads();
  // ---- P2: t[o] = wcpx[v] . fea0 (both row-variants, select by x parity) ----
  {
    int o2 = fg * 2;
    int v0 = (y & 1) << 1;
    int base = __builtin_amdgcn_readfirstlane((v0 * 8 + o2) * 64);
    const float* w00 = wcpx + base;
    const float* w01 = wcpx + base + 64;
    const float* w10 = wcpx + base + 512;
    const float* w11 = wcpx + base + 512 + 64;
    float acc00 = 0.f, acc01 = 0.f, acc10 = 0.f, acc11 = 0.f;
    #pragma unroll
    for (int cb = 0; cb < 8; cb++) {
      h8 blk = *(const h8*)&feat[fswz(px, 64 + cb * 8)];
      #pragma unroll
      for (int q = 0; q < 8; q++) {
        float fv = h2f(blk[q]);
        int c = cb * 8 + q;
        acc00 = fmaf(w00[c], fv, acc00);
        acc01 = fmaf(w01[c], fv, acc01);
        acc10 = fmaf(w10[c], fv, acc10);
        acc11 = fmaf(w11[c], fv, acc11);
      }
    }
    bool odd = (xg & 1);
    t_lds[o2][px]     = odd ? acc10 : acc00;
    t_lds[o2 + 1][px] = odd ? acc11 : acc01;
  }
  __syncthreads();
  // ---- P3: fea = fea0 + wepx[v] @ t (overwrite fea0 slots) ----
  {
    float tv[8];
    #pragma unroll
    for (int oo = 0; oo < 8; oo++) tv[oo] = t_lds[oo][px];
    int v0 = (y & 1) << 1;
    bool odd = (xg & 1);
    int wbase = __builtin_amdgcn_readfirstlane((v0 * 64 + fg * 16) * 8);
    #pragma unroll
    for (int blki = 0; blki < 2; blki++) {
      h8 f0b = *(const h8*)&feat[fswz(px, 64 + fg * 16 + blki * 8)];
      h8 ob2;
      #pragma unroll
      for (int q = 0; q < 8; q++) {
        int k = blki * 8 + q;
        const float* wA = wepx + wbase + k * 8;
        const float* wB = wA + 512;
        float sA = 0.f, sB = 0.f;
        #pragma unroll
        for (int oo = 0; oo < 8; oo++) { sA = fmaf(wA[oo], tv[oo], sA); sB = fmaf(wB[oo], tv[oo], sB); }
        float fe = h2f(f0b[q]) + (odd ? sB : sA);
        ob2[q] = f2h(fe);
      }
      *(h8*)&feat[fswz(px, 64 + fg * 16 + blki * 8)] = ob2;
    }
  }
  __syncthreads();
  // ---- P4: fusion conv via MFMA: [64px x 128] @ [128 x 64] ----
  {
    int l15 = px & 15, lg = px >> 4;
    h8 af[4];
    #pragma unroll
    for (int ks = 0; ks < 4; ks++)
      af[ks] = *(const h8*)&feat[fswz(fg * 16 + l15, lg * 8 + 32 * ks)];
    #pragma unroll
    for (int Nt = 0; Nt < 4; Nt++) {
      f32x4 acc = {0.f, 0.f, 0.f, 0.f};
      #pragma unroll
      for (int ks = 0; ks < 4; ks++) {
        h8 bfv = *(const h8*)&fusB[((Nt * 4 + ks) * 64 + px) * 8];
        acc = __builtin_amdgcn_mfma_f32_16x16x32_f16(af[ks], bfv, acc, 0, 0, 0);
      }
      int c = Nt * 16 + l15;
      float bias = fusb[c];
      float4 o4;
      o4.x = acc[0] + bias; o4.y = acc[1] + bias; o4.z = acc[2] + bias; o4.w = acc[3] + bias;
      float* op = out + ((size_t)(b * 64 + c) * 192 + y) * 192 + xb * 64 + fg * 16 + lg * 4;
      *(float4*)op = o4;
    }
  }
}

// =====================================================================
extern "C" void kernel_launch(void* const* d_in, const int* in_sizes, int n_in,
                              void* d_out, int out_size, void* d_ws, size_t ws_size,
                              hipStream_t stream)
{
  (void)in_sizes; (void)n_in; (void)out_size; (void)ws_size;
  const float* x    = (const float*)d_in[0];
  const float* st   = (const float*)d_in[1];
  const float* kc_w = (const float*)d_in[2];
  const float* kc_b = (const float*)d_in[3];
  const float* wc   = (const float*)d_in[4];
  const float* we   = (const float*)d_in[5];
  const float* b1w  = (const float*)d_in[6];
  const float* b1b  = (const float*)d_in[7];
  const float* b2w  = (const float*)d_in[8];
  const float* b2b  = (const float*)d_in[9];
  const float* rw   = (const float*)d_in[10];
  const float* rb   = (const float*)d_in[11];
  const float* ow   = (const float*)d_in[12];
  const float* ob   = (const float*)d_in[13];
  const float* sow  = (const float*)d_in[14];
  const float* sob  = (const float*)d_in[15];
  const float* fusw = (const float*)d_in[16];
  const float* fusb = (const float*)d_in[17];
  char* ws = (char*)d_ws;
  _Float16* sta  = (_Float16*)(ws + WS_STA);
  int*   gsi  = (int*)(ws + WS_GSI);
  float* gsf  = (float*)(ws + WS_GSF);
  float* wcpxp = (float*)(ws + WS_WCPX);
  float* wepxp = (float*)(ws + WS_WEPX);
  _Float16* fusB = (_Float16*)(ws + WS_FUSB);
  float* kcbp = (float*)(ws + WS_KCB);
  _Float16* kcw = (_Float16*)(ws + WS_KCW);
  float* outp = (float*)d_out;

  k_prep<<<dim3(100), dim3(256), 0, stream>>>(kc_w, kc_b, fusw, kcw, fusB, kcbp);
  k_embed<<<dim3(1), dim3(256), 0, stream>>>(b1w, b1b, b2w, b2b, rw, rb, ow, ob,
                                             sow, sob, wc, we, gsi, gsf, wcpxp, wepxp);
  k_sta<<<dim3(1152), dim3(512), 0, stream>>>(x, st, kcw, kcbp, sta);
  k_main<<<dim3(2304), dim3(256), 0, stream>>>(x, sta, gsi, gsf, wcpxp, wepxp, fusB, fusb, outp);
}

// Round 6
// 215.877 us; speedup vs baseline: 1.2420x; 1.2420x over previous
//
#include <hip/hip_runtime.h>

// ---------- types ----------
typedef __attribute__((ext_vector_type(8))) _Float16 h8;
typedef __attribute__((ext_vector_type(4))) _Float16 h4;
typedef __attribute__((ext_vector_type(4))) float f32x4;

__device__ __forceinline__ _Float16 f2h(float f) { return (_Float16)f; }
__device__ __forceinline__ float h2f(_Float16 h) { return (float)h; }

// swizzled element index into feat LDS tile [px][128] (XOR of i bits 3..5 with px&7)
__device__ __forceinline__ int fswz(int p, int i) { return p * 128 + (i ^ ((p & 7) << 3)); }

// ---------- ws layout (bytes) ----------
// sta is TILE-MAJOR: [b][row 0..95][xtile 0..5][ch 0..63][px 0..15] h16
// tile = 64ch*16px = 1024 h16 = 2048 B, fully written by one k_sta WG.
#define WS_STA   0u          // _Float16 [2304 tiles][1024]      4718592 B
#define WS_GSI   4718592u    // int   [4][4]  {dx,dy,sdx,sdy}
#define WS_GSF   4718656u    // float [4][4]  {wx1,wy1,swx1,swy1}
#define WS_WCPX  4718720u    // float [4][8][64]
#define WS_WEPX  4726912u    // float [4][64][8]
#define WS_FUSB  4735104u    // _Float16 [4][4][64][8]  (fusion B fragments)
#define WS_KCB   4751488u    // float [1600] permuted bias
#define WS_KCW   4757888u    // _Float16 [1600][64] permuted kc_w

// =====================================================================
// k_prep: permute+convert kc_w -> f16 (j' = w*400 + t*16 + cl), permuted
// bias, and fusion-weight B-fragments.
// =====================================================================
__global__ __launch_bounds__(256) void k_prep(
    const float* __restrict__ kc_w, const float* __restrict__ kc_b,
    const float* __restrict__ fusw,
    _Float16* __restrict__ kcw, _Float16* __restrict__ fusB,
    float* __restrict__ kcbp)
{
  int e = blockIdx.x * 256 + threadIdx.x;
  if (e < 25600) {
    int jp = e >> 4, i0 = (e & 15) << 2;
    int w = jp / 400, rem = jp % 400;
    int t = rem >> 4, cl = rem & 15;
    int j = (w * 16 + cl) * 25 + t;           // original row: channel-major c*25+t
    const float4* src = (const float4*)(kc_w + j * 64 + i0);
    float4 v = *src;
    h4 ov;
    ov[0] = f2h(v.x); ov[1] = f2h(v.y); ov[2] = f2h(v.z); ov[3] = f2h(v.w);
    *(h4*)(kcw + jp * 64 + i0) = ov;
  }
  if (e < 8192) {
    // fusB[Nt][ks][lane][j] = fus_w[(Nt*16 + (l&15))*128 + (l>>4)*8 + 32*ks + j]
    int Nt = e >> 11, ks = (e >> 9) & 3, l = (e >> 3) & 63, j = e & 7;
    fusB[e] = f2h(fusw[(Nt * 16 + (l & 15)) * 128 + (l >> 4) * 8 + 32 * ks + j]);
  }
  if (e < 1600) {
    int w = e / 400, rem = e % 400, t = rem >> 4, cl = rem & 15;
    kcbp[e] = kc_b[(w * 16 + cl) * 25 + t];
  }
}

// =====================================================================
// k_embed: the 4 parity variants of the coordinate embedding ->
// grid-sample tables + combined MoE weights.
// =====================================================================
__global__ __launch_bounds__(256) void k_embed(
    const float* __restrict__ b1w, const float* __restrict__ b1b,
    const float* __restrict__ b2w, const float* __restrict__ b2b,
    const float* __restrict__ rw,  const float* __restrict__ rb,
    const float* __restrict__ ow,  const float* __restrict__ ob,
    const float* __restrict__ sow, const float* __restrict__ sob,
    const float* __restrict__ wc,  const float* __restrict__ we,
    int* __restrict__ gs_i, float* __restrict__ gs_f,
    float* __restrict__ wcpx, float* __restrict__ wepx)
{
  __shared__ float l_w2[4096];
  __shared__ float l_h1[4][64];
  __shared__ float l_h2[4][64];
  __shared__ float l_sm[4][8];
  int tid = threadIdx.x;
  for (int e = tid; e < 4096; e += 256) l_w2[e] = b2w[e];
  int g = tid >> 6, o = tid & 63;
  float py = (g >> 1) ? 1.f : 0.f;
  float pxx = (g & 1) ? 1.f : 0.f;
  float chh = (py + 0.5f) * 0.5f;
  float coh = chh - floorf(chh + 0.001f) - 0.5f;
  float cww = (pxx + 0.5f) * 0.5f;
  float cow = cww - floorf(cww + 0.001f) - 0.5f;
  float z = b1b[o] + b1w[o * 4 + 0] * 0.5f + b1w[o * 4 + 1] * 0.5f
          + b1w[o * 4 + 2] * coh + b1w[o * 4 + 3] * cow;
  l_h1[g][o] = fmaxf(z, 0.f);
  __syncthreads();
  float z2 = b2b[o];
  #pragma unroll 8
  for (int i = 0; i < 64; i++) z2 = fmaf(l_w2[o * 64 + i], l_h1[g][i], z2);
  l_h2[g][o] = fmaxf(z2, 0.f);
  __syncthreads();
  if (o < 8) {
    const float* wp; float bias;
    if (o < 4)      { wp = rw  + o * 64;       bias = rb[o]; }
    else if (o < 6) { wp = ow  + (o - 4) * 64; bias = ob[o - 4]; }
    else            { wp = sow + (o - 6) * 64; bias = sob[o - 6]; }
    float acc = bias;
    for (int i = 0; i < 64; i++) acc = fmaf(wp[i], l_h2[g][i], acc);
    if (o < 4) acc = 1.f / (1.f + expf(-acc));
    l_sm[g][o] = acc;
  }
  __syncthreads();
  if (o == 0) {
    float qbx = (g & 1) ? 0.25f : -0.25f;
    float qby = (g >> 1) ? 0.25f : -0.25f;
    float qx  = qbx + l_sm[g][4]; float fx  = floorf(qx);
    float qy  = qby + l_sm[g][5]; float fy  = floorf(qy);
    float qsx = qbx + l_sm[g][6]; float fsx = floorf(qsx);
    float qsy = qby + l_sm[g][7]; float fsy = floorf(qsy);
    gs_i[g * 4 + 0] = (int)fx;  gs_f[g * 4 + 0] = qx - fx;
    gs_i[g * 4 + 1] = (int)fy;  gs_f[g * 4 + 1] = qy - fy;
    gs_i[g * 4 + 2] = (int)fsx; gs_f[g * 4 + 2] = qsx - fsx;
    gs_i[g * 4 + 3] = (int)fsy; gs_f[g * 4 + 3] = qsy - fsy;
  }
  float r0 = l_sm[g][0], r1 = l_sm[g][1], r2 = l_sm[g][2], r3 = l_sm[g][3];
  for (int idx = o; idx < 512; idx += 64) {
    wcpx[g * 512 + idx] = r0 * wc[idx] + r1 * wc[512 + idx] + r2 * wc[1024 + idx] + r3 * wc[1536 + idx];
    wepx[g * 512 + idx] = r0 * we[idx] + r1 * we[512 + idx] + r2 * we[1024 + idx] + r3 * we[1536 + idx];
  }
}

// =====================================================================
// k_sta: fused kernel_warp (f16 MFMA GEMM) + 5x5 spatially-varying conv.
// R6: 256 thr = 4 waves, 16-px tile (1 row x 16 cols), grid 2304 WGs.
// Wave w owns channel group w (16 ch) for the whole 16-px subtile:
// 25 taps x 2 MFMA, kw stays in registers, conv consumes directly.
// launch_bounds(256,4): proven 64-VGPR no-spill budget (R5's (512,8)
// collapsed arch-VGPRs to 32 -> 300 MB scratch spill traffic).
// Epilogue: direct h4 stores into WG-owned 2 KB tile (tile-major).
// =====================================================================
__global__ __launch_bounds__(256, 4) void k_sta(
    const float* __restrict__ x, const float* __restrict__ st,
    const _Float16* __restrict__ kcw, const float* __restrict__ kcbp,
    _Float16* __restrict__ sta_out)
{
  __shared__ __align__(16) _Float16 x_lds[64 * 5 * 24];   // [c][row 0..4][col 0..19 (+pad)]
  __shared__ __align__(16) _Float16 st_lds[16 * 72];      // [px][ch] (+pad)
  int wg = (blockIdx.x & 7) * 288 + (blockIdx.x >> 3);    // XCD-contiguous chunks
  int b = wg / 576;
  int r1 = wg % 576;
  int hb = r1 / 6, wb = r1 % 6;                            // 6 x-tiles of 16 px
  int tid = threadIdx.x, lane = tid & 63, w = tid >> 6;
  // ---- stage x tile (5 rows x 20 cols x 64 ch), float4 interior + scalar edges ----
  // local col i <-> global col 16*wb + i - 2 (replicate-clamped)
  for (int e = tid; e < 1280; e += 256) {           // interior: cols 2..17
    int row = e >> 2, v = e & 3;                    // row = c*5+rr
    int rr = row % 5;
    int grow = min(max(hb + rr - 2, 0), 95);
    float4 val = *(const float4*)&x[((b * 64 + (row / 5)) * 96 + grow) * 96 + 16 * wb + v * 4];
    _Float16* dst = &x_lds[row * 24 + 2 + v * 4];
    dst[0] = f2h(val.x); dst[1] = f2h(val.y); dst[2] = f2h(val.z); dst[3] = f2h(val.w);
  }
  for (int e = tid; e < 1280; e += 256) {           // edges: cols 0,1,18,19
    int row = e >> 2, j = e & 3;
    int col = (j < 2) ? j : 16 + j;
    int rr = row % 5;
    int grow = min(max(hb + rr - 2, 0), 95);
    int gcol = min(max(16 * wb + col - 2, 0), 95);
    x_lds[row * 24 + col] = f2h(x[((b * 64 + (row / 5)) * 96 + grow) * 96 + gcol]);
  }
  // ---- stage st tile (64 ch x 16 px) coalesced, transposed to [px][ch] ----
  {
    int c = tid >> 2, p0 = (tid & 3) * 4;
    float4 v = *(const float4*)&st[((size_t)(b * 64 + c) * 96 + hb) * 96 + 16 * wb + p0];
    st_lds[(p0 + 0) * 72 + c] = f2h(v.x);
    st_lds[(p0 + 1) * 72 + c] = f2h(v.y);
    st_lds[(p0 + 2) * 72 + c] = f2h(v.z);
    st_lds[(p0 + 3) * 72 + c] = f2h(v.w);
  }
  __syncthreads();
  // ---- A fragment from LDS: 16 px x 64 ch, 2 k-steps ----
  int l15 = lane & 15, lg = lane >> 4;
  h8 afrag[2];
  #pragma unroll
  for (int ks = 0; ks < 2; ks++)
    afrag[ks] = *(const h8*)&st_lds[l15 * 72 + 32 * ks + lg * 8];
  // ---- main loop: per tap, MFMA kw (stays in regs) -> conv accumulate ----
  float sta_acc[4];
  #pragma unroll
  for (int r = 0; r < 4; r++) sta_acc[r] = 0.f;
  for (int dh = 0; dh < 5; dh++) {
    // 8 contiguous h16 at local cols [lg*4 .. lg*4+7] of channel w*16+l15
    const _Float16* xp = &x_lds[((w * 16 + l15) * 5 + dh) * 24 + lg * 4];
    h4 xa0 = *(const h4*)xp;
    h4 xa1 = *(const h4*)(xp + 4);
    #pragma unroll
    for (int dw = 0; dw < 5; dw++) {
      int jbase = w * 400 + (dh * 5 + dw) * 16;
      const _Float16* bp = kcw + (jbase + l15) * 64 + lg * 8;
      h8 bf0 = *(const h8*)bp;
      h8 bf1 = *(const h8*)(bp + 32);
      float kb = kcbp[jbase + l15];
      f32x4 acc = {0.f, 0.f, 0.f, 0.f};
      acc = __builtin_amdgcn_mfma_f32_16x16x32_f16(afrag[0], bf0, acc, 0, 0, 0);
      acc = __builtin_amdgcn_mfma_f32_16x16x32_f16(afrag[1], bf1, acc, 0, 0, 0);
      #pragma unroll
      for (int r = 0; r < 4; r++) {
        float kw = acc[r] + kb;
        kw = (kw >= 0.f) ? kw : 0.1f * kw;      // leaky_relu 0.1 (kw stays f32)
        int ci = r + dw;                        // static after unroll
        float xvf = h2f(ci < 4 ? xa0[ci] : xa1[ci - 4]);
        sta_acc[r] = fmaf(kw, xvf, sta_acc[r]);
      }
    }
  }
  // ---- epilogue: direct store into this WG's 2 KB tile (tile-major) ----
  // lane (l15, lg) of wave w: ch = w*16+l15, px = lg*4+r
  {
    h4 ov;
    #pragma unroll
    for (int r = 0; r < 4; r++) ov[r] = f2h(sta_acc[r]);
    _Float16* tp = sta_out + ((size_t)((b * 96 + hb) * 6 + wb) << 10);
    *(h4*)(tp + (w * 16 + l15) * 16 + lg * 4) = ov;
  }
}

// =====================================================================
// k_main: per 64-pixel HR row chunk: grid samples (parity-table stencils),
// MoE (precombined weights, scalar-load), fusion conv via f16 MFMA.
// R6: sta reads use the 16-px tile-major layout.
// =====================================================================
__global__ __launch_bounds__(256) void k_main(
    const float* __restrict__ x, const _Float16* __restrict__ sta,
    const int* __restrict__ gs_i, const float* __restrict__ gs_f,
    const float* __restrict__ wcpx, const float* __restrict__ wepx,
    const _Float16* __restrict__ fusB, const float* __restrict__ fusb,
    float* __restrict__ out)
{
  __shared__ __align__(16) _Float16 feat[64 * 128]; // swizzled [px][0:64 sta_hr | 64:128 fea0->fea]
  __shared__ float t_lds[8][68];
  int wg = (blockIdx.x & 7) * 288 + (blockIdx.x >> 3);  // XCD-contiguous chunks
  int b = wg / 576, r = wg % 576;
  int y = r / 3, xb = r % 3;
  int tid = threadIdx.x, px = tid & 63, fg = tid >> 6;
  int xg = xb * 64 + px;
  int v = ((y & 1) << 1) | (xg & 1);
  int idxo = gs_i[v * 4 + 0], idyo = gs_i[v * 4 + 1], idxs = gs_i[v * 4 + 2], idys = gs_i[v * 4 + 3];
  float wx1 = gs_f[v * 4 + 0], wy1 = gs_f[v * 4 + 1], sx1 = gs_f[v * 4 + 2], sy1 = gs_f[v * 4 + 3];
  int xh = xg >> 1, yh = y >> 1;
  // offset path (fea0 from x)
  int ix0 = xh + idxo, iy0 = yh + idyo;
  float wx0 = 1.f - wx1, wy0 = 1.f - wy1;
  bool vx0 = (unsigned)ix0 < 96u, vx1 = (unsigned)(ix0 + 1) < 96u;
  bool vy0 = (unsigned)iy0 < 96u, vy1 = (unsigned)(iy0 + 1) < 96u;
  int cx0 = min(max(ix0, 0), 95), cx1 = min(max(ix0 + 1, 0), 95);
  int cy0 = min(max(iy0, 0), 95), cy1 = min(max(iy0 + 1, 0), 95);
  float ww00 = (vx0 && vy0) ? wy0 * wx0 : 0.f;
  float ww10 = (vx1 && vy0) ? wy0 * wx1 : 0.f;
  float ww01 = (vx0 && vy1) ? wy1 * wx0 : 0.f;
  float ww11 = (vx1 && vy1) ? wy1 * wx1 : 0.f;
  int a00 = cy0 * 96 + cx0, a10 = cy0 * 96 + cx1, a01 = cy1 * 96 + cx0, a11 = cy1 * 96 + cx1;
  // st_offset path (sta_hr from tile-major sta)
  int jx0 = xh + idxs, jy0 = yh + idys;
  float sx0 = 1.f - sx1, sy0 = 1.f - sy1;
  bool ux0 = (unsigned)jx0 < 96u, ux1 = (unsigned)(jx0 + 1) < 96u;
  bool uy0 = (unsigned)jy0 < 96u, uy1 = (unsigned)(jy0 + 1) < 96u;
  int dx0 = min(max(jx0, 0), 95), dx1 = min(max(jx0 + 1, 0), 95);
  int dy0 = min(max(jy0, 0), 95), dy1 = min(max(jy0 + 1, 0), 95);
  float sw00 = (ux0 && uy0) ? sy0 * sx0 : 0.f;
  float sw10 = (ux1 && uy0) ? sy0 * sx1 : 0.f;
  float sw01 = (ux0 && uy1) ? sy1 * sx0 : 0.f;
  float sw11 = (ux1 && uy1) ? sy1 * sx1 : 0.f;
  // tiled offsets: ((b*96+dy)*6 + dx>>4)*1024 + (dx&15), + ch*16 inside loop
  int s00 = (((b * 96 + dy0) * 6 + (dx0 >> 4)) << 10) + (dx0 & 15);
  int s10 = (((b * 96 + dy0) * 6 + (dx1 >> 4)) << 10) + (dx1 & 15);
  int s01 = (((b * 96 + dy1) * 6 + (dx0 >> 4)) << 10) + (dx0 & 15);
  int s11 = (((b * 96 + dy1) * 6 + (dx1 >> 4)) << 10) + (dx1 & 15);
  // ---- P1: gather sta_hr + fea0, 16 channels per thread-group ----
  h8 stv0, stv1, fev0, fev1;
  #pragma unroll
  for (int k = 0; k < 16; k++) {
    int ch = fg * 16 + k;
    const float* xc = x + (size_t)(b * 64 + ch) * 9216;
    float f0 = ww00 * xc[a00] + ww10 * xc[a10] + ww01 * xc[a01] + ww11 * xc[a11];
    const _Float16* sc = sta + ch * 16;
    float s0 = sw00 * h2f(sc[s00]) + sw10 * h2f(sc[s10]) + sw01 * h2f(sc[s01]) + sw11 * h2f(sc[s11]);
    if (k < 8) { stv0[k] = f2h(s0); fev0[k] = f2h(f0); }
    else       { stv1[k - 8] = f2h(s0); fev1[k - 8] = f2h(f0); }
  }
  *(h8*)&feat[fswz(px, fg * 16)]          = stv0;
  *(h8*)&feat[fswz(px, fg * 16 + 8)]      = stv1;
  *(h8*)&feat[fswz(px, 64 + fg * 16)]     = fev0;
  *(h8*)&feat[fswz(px, 64 + fg * 16 + 8)] = fev1;
  __syncthreads();
  // ---- P2: t[o] = wcpx[v] . fea0 (both row-variants, select by x parity) ----
  {
    int o2 = fg * 2;
    int v0 = (y & 1) << 1;
    int base = __builtin_amdgcn_readfirstlane((v0 * 8 + o2) * 64);
    const float* w00 = wcpx + base;
    const float* w01 = wcpx + base + 64;
    const float* w10 = wcpx + base + 512;
    const float* w11 = wcpx + base + 512 + 64;
    float acc00 = 0.f, acc01 = 0.f, acc10 = 0.f, acc11 = 0.f;
    #pragma unroll
    for (int cb = 0; cb < 8; cb++) {
      h8 blk = *(const h8*)&feat[fswz(px, 64 + cb * 8)];
      #pragma unroll
      for (int q = 0; q < 8; q++) {
        float fv = h2f(blk[q]);
        int c = cb * 8 + q;
        acc00 = fmaf(w00[c], fv, acc00);
        acc01 = fmaf(w01[c], fv, acc01);
        acc10 = fmaf(w10[c], fv, acc10);
        acc11 = fmaf(w11[c], fv, acc11);
      }
    }
    bool odd = (xg & 1);
    t_lds[o2][px]     = odd ? acc10 : acc00;
    t_lds[o2 + 1][px] = odd ? acc11 : acc01;
  }
  __syncthreads();
  // ---- P3: fea = fea0 + wepx[v] @ t (overwrite fea0 slots) ----
  {
    float tv[8];
    #pragma unroll
    for (int oo = 0; oo < 8; oo++) tv[oo] = t_lds[oo][px];
    int v0 = (y & 1) << 1;
    bool odd = (xg & 1);
    int wbase = __builtin_amdgcn_readfirstlane((v0 * 64 + fg * 16) * 8);
    #pragma unroll
    for (int blki = 0; blki < 2; blki++) {
      h8 f0b = *(const h8*)&feat[fswz(px, 64 + fg * 16 + blki * 8)];
      h8 ob2;
      #pragma unroll
      for (int q = 0; q < 8; q++) {
        int k = blki * 8 + q;
        const float* wA = wepx + wbase + k * 8;
        const float* wB = wA + 512;
        float sA = 0.f, sB = 0.f;
        #pragma unroll
        for (int oo = 0; oo < 8; oo++) { sA = fmaf(wA[oo], tv[oo], sA); sB = fmaf(wB[oo], tv[oo], sB); }
        float fe = h2f(f0b[q]) + (odd ? sB : sA);
        ob2[q] = f2h(fe);
      }
      *(h8*)&feat[fswz(px, 64 + fg * 16 + blki * 8)] = ob2;
    }
  }
  __syncthreads();
  // ---- P4: fusion conv via MFMA: [64px x 128] @ [128 x 64] ----
  {
    int l15 = px & 15, lg = px >> 4;
    h8 af[4];
    #pragma unroll
    for (int ks = 0; ks < 4; ks++)
      af[ks] = *(const h8*)&feat[fswz(fg * 16 + l15, lg * 8 + 32 * ks)];
    #pragma unroll
    for (int Nt = 0; Nt < 4; Nt++) {
      f32x4 acc = {0.f, 0.f, 0.f, 0.f};
      #pragma unroll
      for (int ks = 0; ks < 4; ks++) {
        h8 bfv = *(const h8*)&fusB[((Nt * 4 + ks) * 64 + px) * 8];
        acc = __builtin_amdgcn_mfma_f32_16x16x32_f16(af[ks], bfv, acc, 0, 0, 0);
      }
      int c = Nt * 16 + l15;
      float bias = fusb[c];
      float4 o4;
      o4.x = acc[0] + bias; o4.y = acc[1] + bias; o4.z = acc[2] + bias; o4.w = acc[3] + bias;
      float* op = out + ((size_t)(b * 64 + c) * 192 + y) * 192 + xb * 64 + fg * 16 + lg * 4;
      *(float4*)op = o4;
    }
  }
}

// =====================================================================
extern "C" void kernel_launch(void* const* d_in, const int* in_sizes, int n_in,
                              void* d_out, int out_size, void* d_ws, size_t ws_size,
                              hipStream_t stream)
{
  (void)in_sizes; (void)n_in; (void)out_size; (void)ws_size;
  const float* x    = (const float*)d_in[0];
  const float* st   = (const float*)d_in[1];
  const float* kc_w = (const float*)d_in[2];
  const float* kc_b = (const float*)d_in[3];
  const float* wc   = (const float*)d_in[4];
  const float* we   = (const float*)d_in[5];
  const float* b1w  = (const float*)d_in[6];
  const float* b1b  = (const float*)d_in[7];
  const float* b2w  = (const float*)d_in[8];
  const float* b2b  = (const float*)d_in[9];
  const float* rw   = (const float*)d_in[10];
  const float* rb   = (const float*)d_in[11];
  const float* ow   = (const float*)d_in[12];
  const float* ob   = (const float*)d_in[13];
  const float* sow  = (const float*)d_in[14];
  const float* sob  = (const float*)d_in[15];
  const float* fusw = (const float*)d_in[16];
  const float* fusb = (const float*)d_in[17];
  char* ws = (char*)d_ws;
  _Float16* sta  = (_Float16*)(ws + WS_STA);
  int*   gsi  = (int*)(ws + WS_GSI);
  float* gsf  = (float*)(ws + WS_GSF);
  float* wcpxp = (float*)(ws + WS_WCPX);
  float* wepxp = (float*)(ws + WS_WEPX);
  _Float16* fusB = (_Float16*)(ws + WS_FUSB);
  float* kcbp = (float*)(ws + WS_KCB);
  _Float16* kcw = (_Float16*)(ws + WS_KCW);
  float* outp = (float*)d_out;

  k_prep<<<dim3(100), dim3(256), 0, stream>>>(kc_w, kc_b, fusw, kcw, fusB, kcbp);
  k_embed<<<dim3(1), dim3(256), 0, stream>>>(b1w, b1b, b2w, b2b, rw, rb, ow, ob,
                                             sow, sob, wc, we, gsi, gsf, wcpxp, wepxp);
  k_sta<<<dim3(2304), dim3(256), 0, stream>>>(x, st, kcw, kcbp, sta);
  k_main<<<dim3(2304), dim3(256), 0, stream>>>(x, sta, gsi, gsf, wcpxp, wepxp, fusB, fusb, outp);
}

// Round 7
// 208.565 us; speedup vs baseline: 1.2856x; 1.0351x over previous
//
#include <hip/hip_runtime.h>

// ---------- types ----------
typedef __attribute__((ext_vector_type(8))) _Float16 h8;
typedef __attribute__((ext_vector_type(4))) _Float16 h4;
typedef __attribute__((ext_vector_type(4))) float f32x4;

__device__ __forceinline__ _Float16 f2h(float f) { return (_Float16)f; }
__device__ __forceinline__ float h2f(_Float16 h) { return (float)h; }

// swizzled element index into feat LDS tile [px][128] (XOR of i bits 3..5 with px&7)
__device__ __forceinline__ int fswz(int p, int i) { return p * 128 + (i ^ ((p & 7) << 3)); }

// ---------- ws layout (bytes) ----------
// sta is TILE-MAJOR: [b][row 0..95][xtile 0..2][ch 0..63][px 0..31] h16
// tile = 64ch*32px = 2048 h16 = 4096 B, fully written by one k_sta WG.
#define WS_STA   0u          // _Float16 [1152 tiles][2048]      4718592 B
#define WS_GSI   4718592u    // int   [4][4]  {dx,dy,sdx,sdy}
#define WS_GSF   4718656u    // float [4][4]  {wx1,wy1,swx1,swy1}
#define WS_WCPX  4718720u    // float [4][8][64]
#define WS_WEPX  4726912u    // float [4][64][8]
#define WS_FUSB  4735104u    // _Float16 [4][4][64][8]  (fusion B fragments)
#define WS_KCB   4751488u    // float [1600] permuted bias
#define WS_KCW   4757888u    // _Float16 [1600][64] permuted kc_w

// =====================================================================
// k_prep: permute+convert kc_w -> f16 (j' = w*400 + t*16 + cl), permuted
// bias, and fusion-weight B-fragments.
// =====================================================================
__global__ __launch_bounds__(256) void k_prep(
    const float* __restrict__ kc_w, const float* __restrict__ kc_b,
    const float* __restrict__ fusw,
    _Float16* __restrict__ kcw, _Float16* __restrict__ fusB,
    float* __restrict__ kcbp)
{
  int e = blockIdx.x * 256 + threadIdx.x;
  if (e < 25600) {
    int jp = e >> 4, i0 = (e & 15) << 2;
    int w = jp / 400, rem = jp % 400;
    int t = rem >> 4, cl = rem & 15;
    int j = (w * 16 + cl) * 25 + t;           // original row: channel-major c*25+t
    const float4* src = (const float4*)(kc_w + j * 64 + i0);
    float4 v = *src;
    h4 ov;
    ov[0] = f2h(v.x); ov[1] = f2h(v.y); ov[2] = f2h(v.z); ov[3] = f2h(v.w);
    *(h4*)(kcw + jp * 64 + i0) = ov;
  }
  if (e < 8192) {
    // fusB[Nt][ks][lane][j] = fus_w[(Nt*16 + (l&15))*128 + (l>>4)*8 + 32*ks + j]
    int Nt = e >> 11, ks = (e >> 9) & 3, l = (e >> 3) & 63, j = e & 7;
    fusB[e] = f2h(fusw[(Nt * 16 + (l & 15)) * 128 + (l >> 4) * 8 + 32 * ks + j]);
  }
  if (e < 1600) {
    int w = e / 400, rem = e % 400, t = rem >> 4, cl = rem & 15;
    kcbp[e] = kc_b[(w * 16 + cl) * 25 + t];
  }
}

// =====================================================================
// k_embed: the 4 parity variants of the coordinate embedding ->
// grid-sample tables + combined MoE weights.
// =====================================================================
__global__ __launch_bounds__(256) void k_embed(
    const float* __restrict__ b1w, const float* __restrict__ b1b,
    const float* __restrict__ b2w, const float* __restrict__ b2b,
    const float* __restrict__ rw,  const float* __restrict__ rb,
    const float* __restrict__ ow,  const float* __restrict__ ob,
    const float* __restrict__ sow, const float* __restrict__ sob,
    const float* __restrict__ wc,  const float* __restrict__ we,
    int* __restrict__ gs_i, float* __restrict__ gs_f,
    float* __restrict__ wcpx, float* __restrict__ wepx)
{
  __shared__ float l_w2[4096];
  __shared__ float l_h1[4][64];
  __shared__ float l_h2[4][64];
  __shared__ float l_sm[4][8];
  int tid = threadIdx.x;
  for (int e = tid; e < 4096; e += 256) l_w2[e] = b2w[e];
  int g = tid >> 6, o = tid & 63;
  float py = (g >> 1) ? 1.f : 0.f;
  float pxx = (g & 1) ? 1.f : 0.f;
  float chh = (py + 0.5f) * 0.5f;
  float coh = chh - floorf(chh + 0.001f) - 0.5f;
  float cww = (pxx + 0.5f) * 0.5f;
  float cow = cww - floorf(cww + 0.001f) - 0.5f;
  float z = b1b[o] + b1w[o * 4 + 0] * 0.5f + b1w[o * 4 + 1] * 0.5f
          + b1w[o * 4 + 2] * coh + b1w[o * 4 + 3] * cow;
  l_h1[g][o] = fmaxf(z, 0.f);
  __syncthreads();
  float z2 = b2b[o];
  #pragma unroll 8
  for (int i = 0; i < 64; i++) z2 = fmaf(l_w2[o * 64 + i], l_h1[g][i], z2);
  l_h2[g][o] = fmaxf(z2, 0.f);
  __syncthreads();
  if (o < 8) {
    const float* wp; float bias;
    if (o < 4)      { wp = rw  + o * 64;       bias = rb[o]; }
    else if (o < 6) { wp = ow  + (o - 4) * 64; bias = ob[o - 4]; }
    else            { wp = sow + (o - 6) * 64; bias = sob[o - 6]; }
    float acc = bias;
    for (int i = 0; i < 64; i++) acc = fmaf(wp[i], l_h2[g][i], acc);
    if (o < 4) acc = 1.f / (1.f + expf(-acc));
    l_sm[g][o] = acc;
  }
  __syncthreads();
  if (o == 0) {
    float qbx = (g & 1) ? 0.25f : -0.25f;
    float qby = (g >> 1) ? 0.25f : -0.25f;
    float qx  = qbx + l_sm[g][4]; float fx  = floorf(qx);
    float qy  = qby + l_sm[g][5]; float fy  = floorf(qy);
    float qsx = qbx + l_sm[g][6]; float fsx = floorf(qsx);
    float qsy = qby + l_sm[g][7]; float fsy = floorf(qsy);
    gs_i[g * 4 + 0] = (int)fx;  gs_f[g * 4 + 0] = qx - fx;
    gs_i[g * 4 + 1] = (int)fy;  gs_f[g * 4 + 1] = qy - fy;
    gs_i[g * 4 + 2] = (int)fsx; gs_f[g * 4 + 2] = qsx - fsx;
    gs_i[g * 4 + 3] = (int)fsy; gs_f[g * 4 + 3] = qsy - fsy;
  }
  float r0 = l_sm[g][0], r1 = l_sm[g][1], r2 = l_sm[g][2], r3 = l_sm[g][3];
  for (int idx = o; idx < 512; idx += 64) {
    wcpx[g * 512 + idx] = r0 * wc[idx] + r1 * wc[512 + idx] + r2 * wc[1024 + idx] + r3 * wc[1536 + idx];
    wepx[g * 512 + idx] = r0 * we[idx] + r1 * we[512 + idx] + r2 * we[1024 + idx] + r3 * we[1536 + idx];
  }
}

// =====================================================================
// k_sta: fused kernel_warp (f16 MFMA GEMM) + 5x5 spatially-varying conv.
// R7: 512 thr = 8 waves: wave (w = channel group 0..3, half = px subtile
// 0..1), 32-px tile, grid 1152. Max TLP: LDS 30.2 KB -> 5 WGs/CU;
// ~4.5 WG/CU resident x 8 waves = ~32-36 waves/CU.
// launch_bounds(512, 4): VGPR cap 128 (R5's (512,8) forced 32 VGPR ->
// 300 MB scratch spills). Per-dh kb5[] hoist (statically indexed).
// Epilogue: direct h4 stores into WG-owned 4 KB tile-major tile.
// NOTE: WRITE_SIZE ~33 MB in this kernel's window is harness ws-poison
// dirty-line eviction from L2 (layout-independent floor), not our stores.
// =====================================================================
__global__ __launch_bounds__(512, 4) void k_sta(
    const float* __restrict__ x, const float* __restrict__ st,
    const _Float16* __restrict__ kcw, const float* __restrict__ kcbp,
    _Float16* __restrict__ sta_out)
{
  __shared__ __align__(16) _Float16 x_lds[64 * 5 * 40];   // [c][row 0..4][col 0..35 (+pad)]
  __shared__ __align__(16) _Float16 st_lds[32 * 72];      // [px][ch] (+pad)
  int wg = (blockIdx.x & 7) * 144 + (blockIdx.x >> 3);    // XCD-contiguous chunks
  int b = wg / 288;
  int r1 = wg % 288;
  int hb = r1 / 3, wb = r1 % 3;
  int tid = threadIdx.x, lane = tid & 63;
  int w = (tid >> 6) & 3, half = tid >> 8;                // wave = (w, half)
  // ---- stage x tile (5 rows x 36 cols x 64 ch), float4 interior + scalar edges ----
  for (int e = tid; e < 2560; e += 512) {           // interior: cols 2..33
    int row = e >> 3, v = e & 7;                    // row = c*5+rr
    int rr = row % 5;
    int grow = min(max(hb + rr - 2, 0), 95);
    float4 val = *(const float4*)&x[((b * 64 + (row / 5)) * 96 + grow) * 96 + 32 * wb + v * 4];
    _Float16* dst = &x_lds[row * 40 + 2 + v * 4];
    dst[0] = f2h(val.x); dst[1] = f2h(val.y); dst[2] = f2h(val.z); dst[3] = f2h(val.w);
  }
  for (int e = tid; e < 1280; e += 512) {           // edges: cols 0,1,34,35
    int row = e >> 2, j = e & 3;
    int col = (j < 2) ? j : 32 + j;
    int rr = row % 5;
    int grow = min(max(hb + rr - 2, 0), 95);
    int gcol = min(max(32 * wb + col - 2, 0), 95);
    x_lds[row * 40 + col] = f2h(x[((b * 64 + (row / 5)) * 96 + grow) * 96 + gcol]);
  }
  // ---- stage st tile (64 ch x 32 px) coalesced, transposed to [px][ch] ----
  for (int e = tid; e < 512; e += 512) {
    int c = e >> 3, p0 = (e & 7) * 4;
    float4 v = *(const float4*)&st[((size_t)(b * 64 + c) * 96 + hb) * 96 + 32 * wb + p0];
    st_lds[(p0 + 0) * 72 + c] = f2h(v.x);
    st_lds[(p0 + 1) * 72 + c] = f2h(v.y);
    st_lds[(p0 + 2) * 72 + c] = f2h(v.z);
    st_lds[(p0 + 3) * 72 + c] = f2h(v.w);
  }
  __syncthreads();
  // ---- A fragment from LDS: this wave's 16-px subtile, 2 k-steps ----
  int l15 = lane & 15, lg = lane >> 4;
  h8 afrag[2];
  #pragma unroll
  for (int ks = 0; ks < 2; ks++)
    afrag[ks] = *(const h8*)&st_lds[(half * 16 + l15) * 72 + 32 * ks + lg * 8];
  // ---- main loop: per tap, MFMA kw (stays in regs) -> conv accumulate ----
  float sta_acc[4];
  #pragma unroll
  for (int r = 0; r < 4; r++) sta_acc[r] = 0.f;
  for (int dh = 0; dh < 5; dh++) {
    // 8 contiguous h16 at cols [half*16+lg*4 .. +7] of channel w*16+l15
    const _Float16* xp = &x_lds[((w * 16 + l15) * 5 + dh) * 40 + half * 16 + lg * 4];
    h4 xa0 = *(const h4*)xp;
    h4 xa1 = *(const h4*)(xp + 4);
    // hoist the 5 bias gathers for this dh (statically indexed below)
    float kb5[5];
    #pragma unroll
    for (int dw = 0; dw < 5; dw++)
      kb5[dw] = kcbp[w * 400 + (dh * 5 + dw) * 16 + l15];
    #pragma unroll
    for (int dw = 0; dw < 5; dw++) {
      int jbase = w * 400 + (dh * 5 + dw) * 16;
      const _Float16* bp = kcw + (jbase + l15) * 64 + lg * 8;
      h8 bf0 = *(const h8*)bp;
      h8 bf1 = *(const h8*)(bp + 32);
      f32x4 acc = {0.f, 0.f, 0.f, 0.f};
      acc = __builtin_amdgcn_mfma_f32_16x16x32_f16(afrag[0], bf0, acc, 0, 0, 0);
      acc = __builtin_amdgcn_mfma_f32_16x16x32_f16(afrag[1], bf1, acc, 0, 0, 0);
      #pragma unroll
      for (int r = 0; r < 4; r++) {
        float kw = acc[r] + kb5[dw];
        kw = (kw >= 0.f) ? kw : 0.1f * kw;      // leaky_relu 0.1 (kw stays f32)
        int ci = r + dw;                        // static after unroll
        float xvf = h2f(ci < 4 ? xa0[ci] : xa1[ci - 4]);
        sta_acc[r] = fmaf(kw, xvf, sta_acc[r]);
      }
    }
  }
  // ---- epilogue: direct store into this WG's 4 KB tile (tile-major) ----
  // lane (l15, lg) of wave (w, half): ch = w*16+l15, px = half*16+lg*4+r
  {
    h4 ov;
    #pragma unroll
    for (int r = 0; r < 4; r++) ov[r] = f2h(sta_acc[r]);
    _Float16* tp = sta_out + ((size_t)((b * 96 + hb) * 3 + wb) << 11);
    *(h4*)(tp + (w * 16 + l15) * 32 + half * 16 + lg * 4) = ov;
  }
}

// =====================================================================
// k_main: per 64-pixel HR row chunk: grid samples (parity-table stencils),
// MoE (precombined weights, scalar-load), fusion conv via f16 MFMA.
// sta reads use the 32-px tile-major layout.
// =====================================================================
__global__ __launch_bounds__(256) void k_main(
    const float* __restrict__ x, const _Float16* __restrict__ sta,
    const int* __restrict__ gs_i, const float* __restrict__ gs_f,
    const float* __restrict__ wcpx, const float* __restrict__ wepx,
    const _Float16* __restrict__ fusB, const float* __restrict__ fusb,
    float* __restrict__ out)
{
  __shared__ __align__(16) _Float16 feat[64 * 128]; // swizzled [px][0:64 sta_hr | 64:128 fea0->fea]
  __shared__ float t_lds[8][68];
  int wg = (blockIdx.x & 7) * 288 + (blockIdx.x >> 3);  // XCD-contiguous chunks
  int b = wg / 576, r = wg % 576;
  int y = r / 3, xb = r % 3;
  int tid = threadIdx.x, px = tid & 63, fg = tid >> 6;
  int xg = xb * 64 + px;
  int v = ((y & 1) << 1) | (xg & 1);
  int idxo = gs_i[v * 4 + 0], idyo = gs_i[v * 4 + 1], idxs = gs_i[v * 4 + 2], idys = gs_i[v * 4 + 3];
  float wx1 = gs_f[v * 4 + 0], wy1 = gs_f[v * 4 + 1], sx1 = gs_f[v * 4 + 2], sy1 = gs_f[v * 4 + 3];
  int xh = xg >> 1, yh = y >> 1;
  // offset path (fea0 from x)
  int ix0 = xh + idxo, iy0 = yh + idyo;
  float wx0 = 1.f - wx1, wy0 = 1.f - wy1;
  bool vx0 = (unsigned)ix0 < 96u, vx1 = (unsigned)(ix0 + 1) < 96u;
  bool vy0 = (unsigned)iy0 < 96u, vy1 = (unsigned)(iy0 + 1) < 96u;
  int cx0 = min(max(ix0, 0), 95), cx1 = min(max(ix0 + 1, 0), 95);
  int cy0 = min(max(iy0, 0), 95), cy1 = min(max(iy0 + 1, 0), 95);
  float ww00 = (vx0 && vy0) ? wy0 * wx0 : 0.f;
  float ww10 = (vx1 && vy0) ? wy0 * wx1 : 0.f;
  float ww01 = (vx0 && vy1) ? wy1 * wx0 : 0.f;
  float ww11 = (vx1 && vy1) ? wy1 * wx1 : 0.f;
  int a00 = cy0 * 96 + cx0, a10 = cy0 * 96 + cx1, a01 = cy1 * 96 + cx0, a11 = cy1 * 96 + cx1;
  // st_offset path (sta_hr from tile-major sta)
  int jx0 = xh + idxs, jy0 = yh + idys;
  float sx0 = 1.f - sx1, sy0 = 1.f - sy1;
  bool ux0 = (unsigned)jx0 < 96u, ux1 = (unsigned)(jx0 + 1) < 96u;
  bool uy0 = (unsigned)jy0 < 96u, uy1 = (unsigned)(jy0 + 1) < 96u;
  int dx0 = min(max(jx0, 0), 95), dx1 = min(max(jx0 + 1, 0), 95);
  int dy0 = min(max(jy0, 0), 95), dy1 = min(max(jy0 + 1, 0), 95);
  float sw00 = (ux0 && uy0) ? sy0 * sx0 : 0.f;
  float sw10 = (ux1 && uy0) ? sy0 * sx1 : 0.f;
  float sw01 = (ux0 && uy1) ? sy1 * sx0 : 0.f;
  float sw11 = (ux1 && uy1) ? sy1 * sx1 : 0.f;
  // tiled offsets: ((b*96+dy)*3 + dx>>5)*2048 + (dx&31), + ch*32 inside loop
  int s00 = (((b * 96 + dy0) * 3 + (dx0 >> 5)) << 11) + (dx0 & 31);
  int s10 = (((b * 96 + dy0) * 3 + (dx1 >> 5)) << 11) + (dx1 & 31);
  int s01 = (((b * 96 + dy1) * 3 + (dx0 >> 5)) << 11) + (dx0 & 31);
  int s11 = (((b * 96 + dy1) * 3 + (dx1 >> 5)) << 11) + (dx1 & 31);
  // ---- P1: gather sta_hr + fea0, 16 channels per thread-group ----
  h8 stv0, stv1, fev0, fev1;
  #pragma unroll
  for (int k = 0; k < 16; k++) {
    int ch = fg * 16 + k;
    const float* xc = x + (size_t)(b * 64 + ch) * 9216;
    float f0 = ww00 * xc[a00] + ww10 * xc[a10] + ww01 * xc[a01] + ww11 * xc[a11];
    const _Float16* sc = sta + ch * 32;
    float s0 = sw00 * h2f(sc[s00]) + sw10 * h2f(sc[s10]) + sw01 * h2f(sc[s01]) + sw11 * h2f(sc[s11]);
    if (k < 8) { stv0[k] = f2h(s0); fev0[k] = f2h(f0); }
    else       { stv1[k - 8] = f2h(s0); fev1[k - 8] = f2h(f0); }
  }
  *(h8*)&feat[fswz(px, fg * 16)]          = stv0;
  *(h8*)&feat[fswz(px, fg * 16 + 8)]      = stv1;
  *(h8*)&feat[fswz(px, 64 + fg * 16)]     = fev0;
  *(h8*)&feat[fswz(px, 64 + fg * 16 + 8)] = fev1;
  __syncthreads();
  // ---- P2: t[o] = wcpx[v] . fea0 (both row-variants, select by x parity) ----
  {
    int o2 = fg * 2;
    int v0 = (y & 1) << 1;
    int base = __builtin_amdgcn_readfirstlane((v0 * 8 + o2) * 64);
    const float* w00 = wcpx + base;
    const float* w01 = wcpx + base + 64;
    const float* w10 = wcpx + base + 512;
    const float* w11 = wcpx + base + 512 + 64;
    float acc00 = 0.f, acc01 = 0.f, acc10 = 0.f, acc11 = 0.f;
    #pragma unroll
    for (int cb = 0; cb < 8; cb++) {
      h8 blk = *(const h8*)&feat[fswz(px, 64 + cb * 8)];
      #pragma unroll
      for (int q = 0; q < 8; q++) {
        float fv = h2f(blk[q]);
        int c = cb * 8 + q;
        acc00 = fmaf(w00[c], fv, acc00);
        acc01 = fmaf(w01[c], fv, acc01);
        acc10 = fmaf(w10[c], fv, acc10);
        acc11 = fmaf(w11[c], fv, acc11);
      }
    }
    bool odd = (xg & 1);
    t_lds[o2][px]     = odd ? acc10 : acc00;
    t_lds[o2 + 1][px] = odd ? acc11 : acc01;
  }
  __syncthreads();
  // ---- P3: fea = fea0 + wepx[v] @ t (overwrite fea0 slots) ----
  {
    float tv[8];
    #pragma unroll
    for (int oo = 0; oo < 8; oo++) tv[oo] = t_lds[oo][px];
    int v0 = (y & 1) << 1;
    bool odd = (xg & 1);
    int wbase = __builtin_amdgcn_readfirstlane((v0 * 64 + fg * 16) * 8);
    #pragma unroll
    for (int blki = 0; blki < 2; blki++) {
      h8 f0b = *(const h8*)&feat[fswz(px, 64 + fg * 16 + blki * 8)];
      h8 ob2;
      #pragma unroll
      for (int q = 0; q < 8; q++) {
        int k = blki * 8 + q;
        const float* wA = wepx + wbase + k * 8;
        const float* wB = wA + 512;
        float sA = 0.f, sB = 0.f;
        #pragma unroll
        for (int oo = 0; oo < 8; oo++) { sA = fmaf(wA[oo], tv[oo], sA); sB = fmaf(wB[oo], tv[oo], sB); }
        float fe = h2f(f0b[q]) + (odd ? sB : sA);
        ob2[q] = f2h(fe);
      }
      *(h8*)&feat[fswz(px, 64 + fg * 16 + blki * 8)] = ob2;
    }
  }
  __syncthreads();
  // ---- P4: fusion conv via MFMA: [64px x 128] @ [128 x 64] ----
  {
    int l15 = px & 15, lg = px >> 4;
    h8 af[4];
    #pragma unroll
    for (int ks = 0; ks < 4; ks++)
      af[ks] = *(const h8*)&feat[fswz(fg * 16 + l15, lg * 8 + 32 * ks)];
    #pragma unroll
    for (int Nt = 0; Nt < 4; Nt++) {
      f32x4 acc = {0.f, 0.f, 0.f, 0.f};
      #pragma unroll
      for (int ks = 0; ks < 4; ks++) {
        h8 bfv = *(const h8*)&fusB[((Nt * 4 + ks) * 64 + px) * 8];
        acc = __builtin_amdgcn_mfma_f32_16x16x32_f16(af[ks], bfv, acc, 0, 0, 0);
      }
      int c = Nt * 16 + l15;
      float bias = fusb[c];
      float4 o4;
      o4.x = acc[0] + bias; o4.y = acc[1] + bias; o4.z = acc[2] + bias; o4.w = acc[3] + bias;
      float* op = out + ((size_t)(b * 64 + c) * 192 + y) * 192 + xb * 64 + fg * 16 + lg * 4;
      *(float4*)op = o4;
    }
  }
}

// =====================================================================
extern "C" void kernel_launch(void* const* d_in, const int* in_sizes, int n_in,
                              void* d_out, int out_size, void* d_ws, size_t ws_size,
                              hipStream_t stream)
{
  (void)in_sizes; (void)n_in; (void)out_size; (void)ws_size;
  const float* x    = (const float*)d_in[0];
  const float* st   = (const float*)d_in[1];
  const float* kc_w = (const float*)d_in[2];
  const float* kc_b = (const float*)d_in[3];
  const float* wc   = (const float*)d_in[4];
  const float* we   = (const float*)d_in[5];
  const float* b1w  = (const float*)d_in[6];
  const float* b1b  = (const float*)d_in[7];
  const float* b2w  = (const float*)d_in[8];
  const float* b2b  = (const float*)d_in[9];
  const float* rw   = (const float*)d_in[10];
  const float* rb   = (const float*)d_in[11];
  const float* ow   = (const float*)d_in[12];
  const float* ob   = (const float*)d_in[13];
  const float* sow  = (const float*)d_in[14];
  const float* sob  = (const float*)d_in[15];
  const float* fusw = (const float*)d_in[16];
  const float* fusb = (const float*)d_in[17];
  char* ws = (char*)d_ws;
  _Float16* sta  = (_Float16*)(ws + WS_STA);
  int*   gsi  = (int*)(ws + WS_GSI);
  float* gsf  = (float*)(ws + WS_GSF);
  float* wcpxp = (float*)(ws + WS_WCPX);
  float* wepxp = (float*)(ws + WS_WEPX);
  _Float16* fusB = (_Float16*)(ws + WS_FUSB);
  float* kcbp = (float*)(ws + WS_KCB);
  _Float16* kcw = (_Float16*)(ws + WS_KCW);
  float* outp = (float*)d_out;

  k_prep<<<dim3(100), dim3(256), 0, stream>>>(kc_w, kc_b, fusw, kcw, fusB, kcbp);
  k_embed<<<dim3(1), dim3(256), 0, stream>>>(b1w, b1b, b2w, b2b, rw, rb, ow, ob,
                                             sow, sob, wc, we, gsi, gsf, wcpxp, wepxp);
  k_sta<<<dim3(1152), dim3(512), 0, stream>>>(x, st, kcw, kcbp, sta);
  k_main<<<dim3(2304), dim3(256), 0, stream>>>(x, sta, gsi, gsf, wcpxp, wepxp, fusB, fusb, outp);
}

// Round 8
// 197.976 us; speedup vs baseline: 1.3543x; 1.0535x over previous
//
#include <hip/hip_runtime.h>

// ---------- types ----------
typedef __attribute__((ext_vector_type(8))) _Float16 h8;
typedef __attribute__((ext_vector_type(4))) _Float16 h4;
typedef __attribute__((ext_vector_type(4))) float f32x4;

__device__ __forceinline__ _Float16 f2h(float f) { return (_Float16)f; }
__device__ __forceinline__ float h2f(_Float16 h) { return (float)h; }

// swizzled element index into feat LDS tile [px][128] (XOR of i bits 3..5 with px&7)
__device__ __forceinline__ int fswz(int p, int i) { return p * 128 + (i ^ ((p & 7) << 3)); }

// ---------- ws layout (bytes) ----------
// sta is TILE-MAJOR: [b][row][xtile][ch][px 0..31] h16, 4KB per WG tile.
#define WS_STA   0u          // _Float16 [1152 tiles][2048]      4718592 B
#define WS_GSI   4718592u    // int   [4][4]
#define WS_GSF   4718656u    // float [4][4]
#define WS_WCPX  4718720u    // float [4][8][64]
#define WS_WEPX  4726912u    // float [4][64][8]
#define WS_FUSB  4735104u    // _Float16 [4][4][64][8]
#define WS_KCB   4751488u    // float [1600] permuted bias
#define WS_KCW   4757888u    // _Float16 kcw2: [tap 25][w 4][h 2][lane 64][8]  204800 B
                             // = MFMA B-fragments in final lane order

// =====================================================================
// k_prep: kcw -> kcw2 fragment-order f16 blocks, permuted bias, fusB.
// kcw2 block (tap,w): bf_h[lane] = kc_w[row=(w*16+(lane&15))*25+tap]
//                                   [h*32 + (lane>>4)*8 .. +8]
// =====================================================================
__global__ __launch_bounds__(256) void k_prep(
    const float* __restrict__ kc_w, const float* __restrict__ kc_b,
    const float* __restrict__ fusw,
    _Float16* __restrict__ kcw2, _Float16* __restrict__ fusB,
    float* __restrict__ kcbp)
{
  int e = blockIdx.x * 256 + threadIdx.x;
  if (e < 12800) {   // one 16B fragment chunk per thread
    int h = e & 1, lane = (e >> 1) & 63, w = (e >> 7) & 3, tap = e >> 9;
    int l15 = lane & 15, lg = lane >> 4;
    int j = (w * 16 + l15) * 25 + tap;            // original kc_w row (c*25+t)
    const float* s = kc_w + j * 64 + h * 32 + lg * 8;
    h8 ov;
    #pragma unroll
    for (int q = 0; q < 8; q++) ov[q] = f2h(s[q]);
    *(h8*)(kcw2 + ((tap * 4 + w) * 2 + h) * 512 + lane * 8) = ov;
  }
  if (e < 8192) {
    // fusB[Nt][ks][lane][j] = fus_w[(Nt*16 + (l&15))*128 + (l>>4)*8 + 32*ks + j]
    int Nt = e >> 11, ks = (e >> 9) & 3, l = (e >> 3) & 63, j = e & 7;
    fusB[e] = f2h(fusw[(Nt * 16 + (l & 15)) * 128 + (l >> 4) * 8 + 32 * ks + j]);
  }
  if (e < 1600) {
    int w = e / 400, rem = e % 400, t = rem >> 4, cl = rem & 15;
    kcbp[e] = kc_b[(w * 16 + cl) * 25 + t];
  }
}

// =====================================================================
// k_embed: the 4 parity variants of the coordinate embedding ->
// grid-sample tables + combined MoE weights.
// =====================================================================
__global__ __launch_bounds__(256) void k_embed(
    const float* __restrict__ b1w, const float* __restrict__ b1b,
    const float* __restrict__ b2w, const float* __restrict__ b2b,
    const float* __restrict__ rw,  const float* __restrict__ rb,
    const float* __restrict__ ow,  const float* __restrict__ ob,
    const float* __restrict__ sow, const float* __restrict__ sob,
    const float* __restrict__ wc,  const float* __restrict__ we,
    int* __restrict__ gs_i, float* __restrict__ gs_f,
    float* __restrict__ wcpx, float* __restrict__ wepx)
{
  __shared__ float l_w2[4096];
  __shared__ float l_h1[4][64];
  __shared__ float l_h2[4][64];
  __shared__ float l_sm[4][8];
  int tid = threadIdx.x;
  for (int e = tid; e < 4096; e += 256) l_w2[e] = b2w[e];
  int g = tid >> 6, o = tid & 63;
  float py = (g >> 1) ? 1.f : 0.f;
  float pxx = (g & 1) ? 1.f : 0.f;
  float chh = (py + 0.5f) * 0.5f;
  float coh = chh - floorf(chh + 0.001f) - 0.5f;
  float cww = (pxx + 0.5f) * 0.5f;
  float cow = cww - floorf(cww + 0.001f) - 0.5f;
  float z = b1b[o] + b1w[o * 4 + 0] * 0.5f + b1w[o * 4 + 1] * 0.5f
          + b1w[o * 4 + 2] * coh + b1w[o * 4 + 3] * cow;
  l_h1[g][o] = fmaxf(z, 0.f);
  __syncthreads();
  float z2 = b2b[o];
  #pragma unroll 8
  for (int i = 0; i < 64; i++) z2 = fmaf(l_w2[o * 64 + i], l_h1[g][i], z2);
  l_h2[g][o] = fmaxf(z2, 0.f);
  __syncthreads();
  if (o < 8) {
    const float* wp; float bias;
    if (o < 4)      { wp = rw  + o * 64;       bias = rb[o]; }
    else if (o < 6) { wp = ow  + (o - 4) * 64; bias = ob[o - 4]; }
    else            { wp = sow + (o - 6) * 64; bias = sob[o - 6]; }
    float acc = bias;
    for (int i = 0; i < 64; i++) acc = fmaf(wp[i], l_h2[g][i], acc);
    if (o < 4) acc = 1.f / (1.f + expf(-acc));
    l_sm[g][o] = acc;
  }
  __syncthreads();
  if (o == 0) {
    float qbx = (g & 1) ? 0.25f : -0.25f;
    float qby = (g >> 1) ? 0.25f : -0.25f;
    float qx  = qbx + l_sm[g][4]; float fx  = floorf(qx);
    float qy  = qby + l_sm[g][5]; float fy  = floorf(qy);
    float qsx = qbx + l_sm[g][6]; float fsx = floorf(qsx);
    float qsy = qby + l_sm[g][7]; float fsy = floorf(qsy);
    gs_i[g * 4 + 0] = (int)fx;  gs_f[g * 4 + 0] = qx - fx;
    gs_i[g * 4 + 1] = (int)fy;  gs_f[g * 4 + 1] = qy - fy;
    gs_i[g * 4 + 2] = (int)fsx; gs_f[g * 4 + 2] = qsx - fsx;
    gs_i[g * 4 + 3] = (int)fsy; gs_f[g * 4 + 3] = qsy - fsy;
  }
  float r0 = l_sm[g][0], r1 = l_sm[g][1], r2 = l_sm[g][2], r3 = l_sm[g][3];
  for (int idx = o; idx < 512; idx += 64) {
    wcpx[g * 512 + idx] = r0 * wc[idx] + r1 * wc[512 + idx] + r2 * wc[1024 + idx] + r3 * wc[1536 + idx];
    wepx[g * 512 + idx] = r0 * we[idx] + r1 * we[512 + idx] + r2 * we[1024 + idx] + r3 * we[1536 + idx];
  }
}

// =====================================================================
// k_sta: fused kernel_warp (f16 MFMA GEMM) + 5x5 spatially-varying conv.
// R8: per-dh LDS staging of kcw2 (40KB slab, linear 512-thread copy) +
// ds_read_b128 fragment reads. Replaces per-lane L2 loads that caused
// hot-line contention (576 wave-loads/XCD on the same 16 lines per tap).
// Bias staged to LDS once. 8 waves (w=ch-grp, half=px-subtile), 32-px
// tile, tile-major epilogue. launch_bounds(512,4): 128-VGPR cap, no spill.
// =====================================================================
__global__ __launch_bounds__(512, 4) void k_sta(
    const float* __restrict__ x, const float* __restrict__ st,
    const _Float16* __restrict__ kcw2, const float* __restrict__ kcbp,
    _Float16* __restrict__ sta_out)
{
  __shared__ __align__(16) _Float16 x_lds[64 * 5 * 40];   // 25.6 KB
  __shared__ __align__(16) _Float16 st_lds[32 * 72];      // 4.6 KB
  __shared__ __align__(16) _Float16 kw_lds[20480];        // 40 KB: [dw][w][h][lane][8]
  __shared__ float bias_lds[1600];                        // 6.4 KB
  int wg = (blockIdx.x & 7) * 144 + (blockIdx.x >> 3);    // XCD-contiguous chunks
  int b = wg / 288;
  int r1 = wg % 288;
  int hb = r1 / 3, wb = r1 % 3;
  int tid = threadIdx.x, lane = tid & 63;
  int w = (tid >> 6) & 3, half = tid >> 8;                // wave = (w, half)
  // ---- stage x tile (5 rows x 36 cols x 64 ch) ----
  for (int e = tid; e < 2560; e += 512) {           // interior: cols 2..33
    int row = e >> 3, v = e & 7;                    // row = c*5+rr
    int rr = row % 5;
    int grow = min(max(hb + rr - 2, 0), 95);
    float4 val = *(const float4*)&x[((b * 64 + (row / 5)) * 96 + grow) * 96 + 32 * wb + v * 4];
    _Float16* dst = &x_lds[row * 40 + 2 + v * 4];
    dst[0] = f2h(val.x); dst[1] = f2h(val.y); dst[2] = f2h(val.z); dst[3] = f2h(val.w);
  }
  for (int e = tid; e < 1280; e += 512) {           // edges: cols 0,1,34,35
    int row = e >> 2, j = e & 3;
    int col = (j < 2) ? j : 32 + j;
    int rr = row % 5;
    int grow = min(max(hb + rr - 2, 0), 95);
    int gcol = min(max(32 * wb + col - 2, 0), 95);
    x_lds[row * 40 + col] = f2h(x[((b * 64 + (row / 5)) * 96 + grow) * 96 + gcol]);
  }
  // ---- stage st tile (64 ch x 32 px) coalesced, transposed to [px][ch] ----
  if (tid < 512) {
    int c = tid >> 3, p0 = (tid & 7) * 4;
    float4 v = *(const float4*)&st[((size_t)(b * 64 + c) * 96 + hb) * 96 + 32 * wb + p0];
    st_lds[(p0 + 0) * 72 + c] = f2h(v.x);
    st_lds[(p0 + 1) * 72 + c] = f2h(v.y);
    st_lds[(p0 + 2) * 72 + c] = f2h(v.z);
    st_lds[(p0 + 3) * 72 + c] = f2h(v.w);
  }
  // ---- stage bias (1600 floats) ----
  if (tid < 400) *(float4*)&bias_lds[tid * 4] = *(const float4*)&kcbp[tid * 4];
  __syncthreads();
  // ---- A fragment from LDS: this wave's 16-px subtile, 2 k-steps ----
  int l15 = lane & 15, lg = lane >> 4;
  h8 afrag[2];
  #pragma unroll
  for (int ks = 0; ks < 2; ks++)
    afrag[ks] = *(const h8*)&st_lds[(half * 16 + l15) * 72 + 32 * ks + lg * 8];
  // ---- main loop over dh: stage 40KB kcw2 slab -> 5 taps of MFMA+conv ----
  float sta_acc[4];
  #pragma unroll
  for (int r = 0; r < 4; r++) sta_acc[r] = 0.f;
  for (int dh = 0; dh < 5; dh++) {
    if (dh) __syncthreads();                  // previous slab's reads done
    {
      const uint4* src = (const uint4*)((const char*)kcw2 + dh * 40960);
      uint4* dst = (uint4*)kw_lds;
      #pragma unroll
      for (int s = 0; s < 5; s++)
        dst[s * 512 + tid] = src[s * 512 + tid];
    }
    __syncthreads();
    // x row values for this dh (8 contiguous h16)
    const _Float16* xp = &x_lds[((w * 16 + l15) * 5 + dh) * 40 + half * 16 + lg * 4];
    h4 xa0 = *(const h4*)xp;
    h4 xa1 = *(const h4*)(xp + 4);
    float kb5[5];
    #pragma unroll
    for (int dw = 0; dw < 5; dw++)
      kb5[dw] = bias_lds[w * 400 + (dh * 5 + dw) * 16 + l15];
    #pragma unroll
    for (int dw = 0; dw < 5; dw++) {
      h8 bf0 = *(const h8*)&kw_lds[(dw * 4 + w) * 1024 + lane * 8];
      h8 bf1 = *(const h8*)&kw_lds[(dw * 4 + w) * 1024 + 512 + lane * 8];
      f32x4 acc = {0.f, 0.f, 0.f, 0.f};
      acc = __builtin_amdgcn_mfma_f32_16x16x32_f16(afrag[0], bf0, acc, 0, 0, 0);
      acc = __builtin_amdgcn_mfma_f32_16x16x32_f16(afrag[1], bf1, acc, 0, 0, 0);
      #pragma unroll
      for (int r = 0; r < 4; r++) {
        float kw = acc[r] + kb5[dw];
        kw = (kw >= 0.f) ? kw : 0.1f * kw;      // leaky_relu 0.1
        int ci = r + dw;                        // static after unroll
        float xvf = h2f(ci < 4 ? xa0[ci] : xa1[ci - 4]);
        sta_acc[r] = fmaf(kw, xvf, sta_acc[r]);
      }
    }
  }
  // ---- epilogue: direct store into this WG's 4 KB tile (tile-major) ----
  {
    h4 ov;
    #pragma unroll
    for (int r = 0; r < 4; r++) ov[r] = f2h(sta_acc[r]);
    _Float16* tp = sta_out + ((size_t)((b * 96 + hb) * 3 + wb) << 11);
    *(h4*)(tp + (w * 16 + l15) * 32 + half * 16 + lg * 4) = ov;
  }
}

// =====================================================================
// k_main: per 64-pixel HR row chunk: grid samples (parity-table stencils),
// MoE (precombined weights, scalar-load), fusion conv via f16 MFMA.
// sta reads use the 32-px tile-major layout. (unchanged from R7)
// =====================================================================
__global__ __launch_bounds__(256) void k_main(
    const float* __restrict__ x, const _Float16* __restrict__ sta,
    const int* __restrict__ gs_i, const float* __restrict__ gs_f,
    const float* __restrict__ wcpx, const float* __restrict__ wepx,
    const _Float16* __restrict__ fusB, const float* __restrict__ fusb,
    float* __restrict__ out)
{
  __shared__ __align__(16) _Float16 feat[64 * 128]; // swizzled [px][0:64 sta_hr | 64:128 fea0->fea]
  __shared__ float t_lds[8][68];
  int wg = (blockIdx.x & 7) * 288 + (blockIdx.x >> 3);  // XCD-contiguous chunks
  int b = wg / 576, r = wg % 576;
  int y = r / 3, xb = r % 3;
  int tid = threadIdx.x, px = tid & 63, fg = tid >> 6;
  int xg = xb * 64 + px;
  int v = ((y & 1) << 1) | (xg & 1);
  int idxo = gs_i[v * 4 + 0], idyo = gs_i[v * 4 + 1], idxs = gs_i[v * 4 + 2], idys = gs_i[v * 4 + 3];
  float wx1 = gs_f[v * 4 + 0], wy1 = gs_f[v * 4 + 1], sx1 = gs_f[v * 4 + 2], sy1 = gs_f[v * 4 + 3];
  int xh = xg >> 1, yh = y >> 1;
  // offset path (fea0 from x)
  int ix0 = xh + idxo, iy0 = yh + idyo;
  float wx0 = 1.f - wx1, wy0 = 1.f - wy1;
  bool vx0 = (unsigned)ix0 < 96u, vx1 = (unsigned)(ix0 + 1) < 96u;
  bool vy0 = (unsigned)iy0 < 96u, vy1 = (unsigned)(iy0 + 1) < 96u;
  int cx0 = min(max(ix0, 0), 95), cx1 = min(max(ix0 + 1, 0), 95);
  int cy0 = min(max(iy0, 0), 95), cy1 = min(max(iy0 + 1, 0), 95);
  float ww00 = (vx0 && vy0) ? wy0 * wx0 : 0.f;
  float ww10 = (vx1 && vy0) ? wy0 * wx1 : 0.f;
  float ww01 = (vx0 && vy1) ? wy1 * wx0 : 0.f;
  float ww11 = (vx1 && vy1) ? wy1 * wx1 : 0.f;
  int a00 = cy0 * 96 + cx0, a10 = cy0 * 96 + cx1, a01 = cy1 * 96 + cx0, a11 = cy1 * 96 + cx1;
  // st_offset path (sta_hr from tile-major sta)
  int jx0 = xh + idxs, jy0 = yh + idys;
  float sx0 = 1.f - sx1, sy0 = 1.f - sy1;
  bool ux0 = (unsigned)jx0 < 96u, ux1 = (unsigned)(jx0 + 1) < 96u;
  bool uy0 = (unsigned)jy0 < 96u, uy1 = (unsigned)(jy0 + 1) < 96u;
  int dx0 = min(max(jx0, 0), 95), dx1 = min(max(jx0 + 1, 0), 95);
  int dy0 = min(max(jy0, 0), 95), dy1 = min(max(jy0 + 1, 0), 95);
  float sw00 = (ux0 && uy0) ? sy0 * sx0 : 0.f;
  float sw10 = (ux1 && uy0) ? sy0 * sx1 : 0.f;
  float sw01 = (ux0 && uy1) ? sy1 * sx0 : 0.f;
  float sw11 = (ux1 && uy1) ? sy1 * sx1 : 0.f;
  int s00 = (((b * 96 + dy0) * 3 + (dx0 >> 5)) << 11) + (dx0 & 31);
  int s10 = (((b * 96 + dy0) * 3 + (dx1 >> 5)) << 11) + (dx1 & 31);
  int s01 = (((b * 96 + dy1) * 3 + (dx0 >> 5)) << 11) + (dx0 & 31);
  int s11 = (((b * 96 + dy1) * 3 + (dx1 >> 5)) << 11) + (dx1 & 31);
  // ---- P1: gather sta_hr + fea0, 16 channels per thread-group ----
  h8 stv0, stv1, fev0, fev1;
  #pragma unroll
  for (int k = 0; k < 16; k++) {
    int ch = fg * 16 + k;
    const float* xc = x + (size_t)(b * 64 + ch) * 9216;
    float f0 = ww00 * xc[a00] + ww10 * xc[a10] + ww01 * xc[a01] + ww11 * xc[a11];
    const _Float16* sc = sta + ch * 32;
    float s0 = sw00 * h2f(sc[s00]) + sw10 * h2f(sc[s10]) + sw01 * h2f(sc[s01]) + sw11 * h2f(sc[s11]);
    if (k < 8) { stv0[k] = f2h(s0); fev0[k] = f2h(f0); }
    else       { stv1[k - 8] = f2h(s0); fev1[k - 8] = f2h(f0); }
  }
  *(h8*)&feat[fswz(px, fg * 16)]          = stv0;
  *(h8*)&feat[fswz(px, fg * 16 + 8)]      = stv1;
  *(h8*)&feat[fswz(px, 64 + fg * 16)]     = fev0;
  *(h8*)&feat[fswz(px, 64 + fg * 16 + 8)] = fev1;
  __syncthreads();
  // ---- P2: t[o] = wcpx[v] . fea0 (both row-variants, select by x parity) ----
  {
    int o2 = fg * 2;
    int v0 = (y & 1) << 1;
    int base = __builtin_amdgcn_readfirstlane((v0 * 8 + o2) * 64);
    const float* w00 = wcpx + base;
    const float* w01 = wcpx + base + 64;
    const float* w10 = wcpx + base + 512;
    const float* w11 = wcpx + base + 512 + 64;
    float acc00 = 0.f, acc01 = 0.f, acc10 = 0.f, acc11 = 0.f;
    #pragma unroll
    for (int cb = 0; cb < 8; cb++) {
      h8 blk = *(const h8*)&feat[fswz(px, 64 + cb * 8)];
      #pragma unroll
      for (int q = 0; q < 8; q++) {
        float fv = h2f(blk[q]);
        int c = cb * 8 + q;
        acc00 = fmaf(w00[c], fv, acc00);
        acc01 = fmaf(w01[c], fv, acc01);
        acc10 = fmaf(w10[c], fv, acc10);
        acc11 = fmaf(w11[c], fv, acc11);
      }
    }
    bool odd = (xg & 1);
    t_lds[o2][px]     = odd ? acc10 : acc00;
    t_lds[o2 + 1][px] = odd ? acc11 : acc01;
  }
  __syncthreads();
  // ---- P3: fea = fea0 + wepx[v] @ t (overwrite fea0 slots) ----
  {
    float tv[8];
    #pragma unroll
    for (int oo = 0; oo < 8; oo++) tv[oo] = t_lds[oo][px];
    int v0 = (y & 1) << 1;
    bool odd = (xg & 1);
    int wbase = __builtin_amdgcn_readfirstlane((v0 * 64 + fg * 16) * 8);
    #pragma unroll
    for (int blki = 0; blki < 2; blki++) {
      h8 f0b = *(const h8*)&feat[fswz(px, 64 + fg * 16 + blki * 8)];
      h8 ob2;
      #pragma unroll
      for (int q = 0; q < 8; q++) {
        int k = blki * 8 + q;
        const float* wA = wepx + wbase + k * 8;
        const float* wB = wA + 512;
        float sA = 0.f, sB = 0.f;
        #pragma unroll
        for (int oo = 0; oo < 8; oo++) { sA = fmaf(wA[oo], tv[oo], sA); sB = fmaf(wB[oo], tv[oo], sB); }
        float fe = h2f(f0b[q]) + (odd ? sB : sA);
        ob2[q] = f2h(fe);
      }
      *(h8*)&feat[fswz(px, 64 + fg * 16 + blki * 8)] = ob2;
    }
  }
  __syncthreads();
  // ---- P4: fusion conv via MFMA: [64px x 128] @ [128 x 64] ----
  {
    int l15 = px & 15, lg = px >> 4;
    h8 af[4];
    #pragma unroll
    for (int ks = 0; ks < 4; ks++)
      af[ks] = *(const h8*)&feat[fswz(fg * 16 + l15, lg * 8 + 32 * ks)];
    #pragma unroll
    for (int Nt = 0; Nt < 4; Nt++) {
      f32x4 acc = {0.f, 0.f, 0.f, 0.f};
      #pragma unroll
      for (int ks = 0; ks < 4; ks++) {
        h8 bfv = *(const h8*)&fusB[((Nt * 4 + ks) * 64 + px) * 8];
        acc = __builtin_amdgcn_mfma_f32_16x16x32_f16(af[ks], bfv, acc, 0, 0, 0);
      }
      int c = Nt * 16 + l15;
      float bias = fusb[c];
      float4 o4;
      o4.x = acc[0] + bias; o4.y = acc[1] + bias; o4.z = acc[2] + bias; o4.w = acc[3] + bias;
      float* op = out + ((size_t)(b * 64 + c) * 192 + y) * 192 + xb * 64 + fg * 16 + lg * 4;
      *(float4*)op = o4;
    }
  }
}

// =====================================================================
extern "C" void kernel_launch(void* const* d_in, const int* in_sizes, int n_in,
                              void* d_out, int out_size, void* d_ws, size_t ws_size,
                              hipStream_t stream)
{
  (void)in_sizes; (void)n_in; (void)out_size; (void)ws_size;
  const float* x    = (const float*)d_in[0];
  const float* st   = (const float*)d_in[1];
  const float* kc_w = (const float*)d_in[2];
  const float* kc_b = (const float*)d_in[3];
  const float* wc   = (const float*)d_in[4];
  const float* we   = (const float*)d_in[5];
  const float* b1w  = (const float*)d_in[6];
  const float* b1b  = (const float*)d_in[7];
  const float* b2w  = (const float*)d_in[8];
  const float* b2b  = (const float*)d_in[9];
  const float* rw   = (const float*)d_in[10];
  const float* rb   = (const float*)d_in[11];
  const float* ow   = (const float*)d_in[12];
  const float* ob   = (const float*)d_in[13];
  const float* sow  = (const float*)d_in[14];
  const float* sob  = (const float*)d_in[15];
  const float* fusw = (const float*)d_in[16];
  const float* fusb = (const float*)d_in[17];
  char* ws = (char*)d_ws;
  _Float16* sta  = (_Float16*)(ws + WS_STA);
  int*   gsi  = (int*)(ws + WS_GSI);
  float* gsf  = (float*)(ws + WS_GSF);
  float* wcpxp = (float*)(ws + WS_WCPX);
  float* wepxp = (float*)(ws + WS_WEPX);
  _Float16* fusB = (_Float16*)(ws + WS_FUSB);
  float* kcbp = (float*)(ws + WS_KCB);
  _Float16* kcw2 = (_Float16*)(ws + WS_KCW);
  float* outp = (float*)d_out;

  k_prep<<<dim3(100), dim3(256), 0, stream>>>(kc_w, kc_b, fusw, kcw2, fusB, kcbp);
  k_embed<<<dim3(1), dim3(256), 0, stream>>>(b1w, b1b, b2w, b2b, rw, rb, ow, ob,
                                             sow, sob, wc, we, gsi, gsf, wcpxp, wepxp);
  k_sta<<<dim3(1152), dim3(512), 0, stream>>>(x, st, kcw2, kcbp, sta);
  k_main<<<dim3(2304), dim3(256), 0, stream>>>(x, sta, gsi, gsf, wcpxp, wepxp, fusB, fusb, outp);
}

// Round 10
// 170.287 us; speedup vs baseline: 1.5745x; 1.1626x over previous
//
#include <hip/hip_runtime.h>

// ---------- types ----------
typedef __attribute__((ext_vector_type(8))) _Float16 h8;
typedef __attribute__((ext_vector_type(4))) _Float16 h4;
typedef __attribute__((ext_vector_type(4))) float f32x4;

__device__ __forceinline__ _Float16 f2h(float f) { return (_Float16)f; }
__device__ __forceinline__ float h2f(_Float16 h) { return (float)h; }

// swizzled element index into feat LDS tile [px][128] (XOR of i bits 3..5 with px&7)
__device__ __forceinline__ int fswz(int p, int i) { return p * 128 + (i ^ ((p & 7) << 3)); }

// ---------- ws layout (bytes) ----------
// sta is TILE-MAJOR: [b][row][xtile][ch][px 0..31] h16, 4KB per WG tile.
#define WS_STA   0u          // _Float16 [1152 tiles][2048]      4718592 B
#define WS_GSI   4718592u    // int   [4][4]
#define WS_GSF   4718656u    // float [4][4]
#define WS_WCPX  4718720u    // float [4][8][64]
#define WS_WEPX  4726912u    // float [4][64][8]
#define WS_FUSB  4735104u    // _Float16 [4][4][64][8]
#define WS_KCB   4751488u    // float [1600] permuted bias
#define WS_KCW   4757888u    // _Float16 kcw2: [tap 25][w 4][h 2][lane 64][8]  204800 B
                             // = MFMA B-fragments in final lane order (1KB coalesced/frag)

// =====================================================================
// k_prep: kcw -> kcw2 fragment-order f16 blocks, permuted bias, fusB.
// kcw2 block (tap,w): bf_h[lane] = kc_w[row=(w*16+(lane&15))*25+tap]
//                                   [h*32 + (lane>>4)*8 .. +8]
// =====================================================================
__global__ __launch_bounds__(256) void k_prep(
    const float* __restrict__ kc_w, const float* __restrict__ kc_b,
    const float* __restrict__ fusw,
    _Float16* __restrict__ kcw2, _Float16* __restrict__ fusB,
    float* __restrict__ kcbp)
{
  int e = blockIdx.x * 256 + threadIdx.x;
  if (e < 12800) {   // one 16B fragment chunk per thread
    int h = e & 1, lane = (e >> 1) & 63, w = (e >> 7) & 3, tap = e >> 9;
    int l15 = lane & 15, lg = lane >> 4;
    int j = (w * 16 + l15) * 25 + tap;            // original kc_w row (c*25+t)
    const float* s = kc_w + j * 64 + h * 32 + lg * 8;
    h8 ov;
    #pragma unroll
    for (int q = 0; q < 8; q++) ov[q] = f2h(s[q]);
    *(h8*)(kcw2 + ((tap * 4 + w) * 2 + h) * 512 + lane * 8) = ov;
  }
  if (e < 8192) {
    // fusB[Nt][ks][lane][j] = fus_w[(Nt*16 + (l&15))*128 + (l>>4)*8 + 32*ks + j]
    int Nt = e >> 11, ks = (e >> 9) & 3, l = (e >> 3) & 63, j = e & 7;
    fusB[e] = f2h(fusw[(Nt * 16 + (l & 15)) * 128 + (l >> 4) * 8 + 32 * ks + j]);
  }
  if (e < 1600) {
    int w = e / 400, rem = e % 400, t = rem >> 4, cl = rem & 15;
    kcbp[e] = kc_b[(w * 16 + cl) * 25 + t];
  }
}

// =====================================================================
// k_embed: the 4 parity variants of the coordinate embedding ->
// grid-sample tables + combined MoE weights.
// =====================================================================
__global__ __launch_bounds__(256) void k_embed(
    const float* __restrict__ b1w, const float* __restrict__ b1b,
    const float* __restrict__ b2w, const float* __restrict__ b2b,
    const float* __restrict__ rw,  const float* __restrict__ rb,
    const float* __restrict__ ow,  const float* __restrict__ ob,
    const float* __restrict__ sow, const float* __restrict__ sob,
    const float* __restrict__ wc,  const float* __restrict__ we,
    int* __restrict__ gs_i, float* __restrict__ gs_f,
    float* __restrict__ wcpx, float* __restrict__ wepx)
{
  __shared__ float l_w2[4096];
  __shared__ float l_h1[4][64];
  __shared__ float l_h2[4][64];
  __shared__ float l_sm[4][8];
  int tid = threadIdx.x;
  for (int e = tid; e < 4096; e += 256) l_w2[e] = b2w[e];
  int g = tid >> 6, o = tid & 63;
  float py = (g >> 1) ? 1.f : 0.f;
  float pxx = (g & 1) ? 1.f : 0.f;
  float chh = (py + 0.5f) * 0.5f;
  float coh = chh - floorf(chh + 0.001f) - 0.5f;
  float cww = (pxx + 0.5f) * 0.5f;
  float cow = cww - floorf(cww + 0.001f) - 0.5f;
  float z = b1b[o] + b1w[o * 4 + 0] * 0.5f + b1w[o * 4 + 1] * 0.5f
          + b1w[o * 4 + 2] * coh + b1w[o * 4 + 3] * cow;
  l_h1[g][o] = fmaxf(z, 0.f);
  __syncthreads();
  float z2 = b2b[o];
  #pragma unroll 8
  for (int i = 0; i < 64; i++) z2 = fmaf(l_w2[o * 64 + i], l_h1[g][i], z2);
  l_h2[g][o] = fmaxf(z2, 0.f);
  __syncthreads();
  if (o < 8) {
    const float* wp; float bias;
    if (o < 4)      { wp = rw  + o * 64;       bias = rb[o]; }
    else if (o < 6) { wp = ow  + (o - 4) * 64; bias = ob[o - 4]; }
    else            { wp = sow + (o - 6) * 64; bias = sob[o - 6]; }
    float acc = bias;
    for (int i = 0; i < 64; i++) acc = fmaf(wp[i], l_h2[g][i], acc);
    if (o < 4) acc = 1.f / (1.f + expf(-acc));
    l_sm[g][o] = acc;
  }
  __syncthreads();
  if (o == 0) {
    float qbx = (g & 1) ? 0.25f : -0.25f;
    float qby = (g >> 1) ? 0.25f : -0.25f;
    float qx  = qbx + l_sm[g][4]; float fx  = floorf(qx);
    float qy  = qby + l_sm[g][5]; float fy  = floorf(qy);
    float qsx = qbx + l_sm[g][6]; float fsx = floorf(qsx);
    float qsy = qby + l_sm[g][7]; float fsy = floorf(qsy);
    gs_i[g * 4 + 0] = (int)fx;  gs_f[g * 4 + 0] = qx - fx;
    gs_i[g * 4 + 1] = (int)fy;  gs_f[g * 4 + 1] = qy - fy;
    gs_i[g * 4 + 2] = (int)fsx; gs_f[g * 4 + 2] = qsx - fsx;
    gs_i[g * 4 + 3] = (int)fsy; gs_f[g * 4 + 3] = qsy - fsy;
  }
  float r0 = l_sm[g][0], r1 = l_sm[g][1], r2 = l_sm[g][2], r3 = l_sm[g][3];
  for (int idx = o; idx < 512; idx += 64) {
    wcpx[g * 512 + idx] = r0 * wc[idx] + r1 * wc[512 + idx] + r2 * wc[1024 + idx] + r3 * wc[1536 + idx];
    wepx[g * 512 + idx] = r0 * we[idx] + r1 * we[512 + idx] + r2 * we[1024 + idx] + r3 * we[1536 + idx];
  }
}

// =====================================================================
// k_sta: fused kernel_warp (f16 MFMA GEMM) + 5x5 spatially-varying conv.
// R9: fragment loads go DIRECTLY global->VGPR from kcw2 (one coalesced
// 1KB load per fragment: 8 lines, L2/L3-hot) with the FULL 25-tap loop
// unrolled and ZERO barriers in the main loop -> compiler software-
// pipelines the 50 loads across MFMAs. Bias pre-hoisted to kb[25] regs
// (static index after unroll). LDS back to 30 KB (no kw slab).
// 8 waves (w=ch-grp, half=px-subtile), 32-px tile, tile-major epilogue.
// =====================================================================
__global__ __launch_bounds__(512, 4) void k_sta(
    const float* __restrict__ x, const float* __restrict__ st,
    const _Float16* __restrict__ kcw2, const float* __restrict__ kcbp,
    _Float16* __restrict__ sta_out)
{
  __shared__ __align__(16) _Float16 x_lds[64 * 5 * 40];   // 25.6 KB
  __shared__ __align__(16) _Float16 st_lds[32 * 72];      // 4.6 KB
  int wg = (blockIdx.x & 7) * 144 + (blockIdx.x >> 3);    // XCD-contiguous chunks
  int b = wg / 288;
  int r1 = wg % 288;
  int hb = r1 / 3, wb = r1 % 3;
  int tid = threadIdx.x, lane = tid & 63;
  int w = (tid >> 6) & 3, half = tid >> 8;                // wave = (w, half)
  // ---- stage x tile (5 rows x 36 cols x 64 ch) ----
  for (int e = tid; e < 2560; e += 512) {           // interior: cols 2..33
    int row = e >> 3, v = e & 7;                    // row = c*5+rr
    int rr = row % 5;
    int grow = min(max(hb + rr - 2, 0), 95);
    float4 val = *(const float4*)&x[((b * 64 + (row / 5)) * 96 + grow) * 96 + 32 * wb + v * 4];
    _Float16* dst = &x_lds[row * 40 + 2 + v * 4];
    dst[0] = f2h(val.x); dst[1] = f2h(val.y); dst[2] = f2h(val.z); dst[3] = f2h(val.w);
  }
  for (int e = tid; e < 1280; e += 512) {           // edges: cols 0,1,34,35
    int row = e >> 2, j = e & 3;
    int col = (j < 2) ? j : 32 + j;
    int rr = row % 5;
    int grow = min(max(hb + rr - 2, 0), 95);
    int gcol = min(max(32 * wb + col - 2, 0), 95);
    x_lds[row * 40 + col] = f2h(x[((b * 64 + (row / 5)) * 96 + grow) * 96 + gcol]);
  }
  // ---- stage st tile (64 ch x 32 px) coalesced, transposed to [px][ch] ----
  {
    int c = tid >> 3, p0 = (tid & 7) * 4;
    float4 v = *(const float4*)&st[((size_t)(b * 64 + c) * 96 + hb) * 96 + 32 * wb + p0];
    st_lds[(p0 + 0) * 72 + c] = f2h(v.x);
    st_lds[(p0 + 1) * 72 + c] = f2h(v.y);
    st_lds[(p0 + 2) * 72 + c] = f2h(v.z);
    st_lds[(p0 + 3) * 72 + c] = f2h(v.w);
  }
  int l15 = lane & 15, lg = lane >> 4;
  // ---- bias: hoist all 25 taps to registers (static after full unroll) ----
  float kb[25];
  #pragma unroll
  for (int t = 0; t < 25; t++) kb[t] = kcbp[w * 400 + t * 16 + l15];
  __syncthreads();
  // ---- A fragment from LDS: this wave's 16-px subtile, 2 k-steps ----
  h8 afrag[2];
  #pragma unroll
  for (int ks = 0; ks < 2; ks++)
    afrag[ks] = *(const h8*)&st_lds[(half * 16 + l15) * 72 + 32 * ks + lg * 8];
  // ---- main loop: FULLY UNROLLED 25 taps, no barriers ----
  float sta_acc[4];
  #pragma unroll
  for (int r = 0; r < 4; r++) sta_acc[r] = 0.f;
  #pragma unroll
  for (int dh = 0; dh < 5; dh++) {
    const _Float16* xp = &x_lds[((w * 16 + l15) * 5 + dh) * 40 + half * 16 + lg * 4];
    h4 xa0 = *(const h4*)xp;
    h4 xa1 = *(const h4*)(xp + 4);
    #pragma unroll
    for (int dw = 0; dw < 5; dw++) {
      int t = dh * 5 + dw;
      const _Float16* bp = kcw2 + (size_t)(t * 4 + w) * 1024 + lane * 8;
      h8 bf0 = *(const h8*)bp;             // coalesced 1KB wave load
      h8 bf1 = *(const h8*)(bp + 512);     // coalesced 1KB wave load
      f32x4 acc = {0.f, 0.f, 0.f, 0.f};
      acc = __builtin_amdgcn_mfma_f32_16x16x32_f16(afrag[0], bf0, acc, 0, 0, 0);
      acc = __builtin_amdgcn_mfma_f32_16x16x32_f16(afrag[1], bf1, acc, 0, 0, 0);
      #pragma unroll
      for (int r = 0; r < 4; r++) {
        float kw = acc[r] + kb[t];
        kw = (kw >= 0.f) ? kw : 0.1f * kw;      // leaky_relu 0.1
        int ci = r + dw;                        // static after unroll
        float xvf = h2f(ci < 4 ? xa0[ci] : xa1[ci - 4]);
        sta_acc[r] = fmaf(kw, xvf, sta_acc[r]);
      }
    }
  }
  // ---- epilogue: direct store into this WG's 4 KB tile (tile-major) ----
  {
    h4 ov;
    #pragma unroll
    for (int r = 0; r < 4; r++) ov[r] = f2h(sta_acc[r]);
    _Float16* tp = sta_out + ((size_t)((b * 96 + hb) * 3 + wb) << 11);
    *(h4*)(tp + (w * 16 + l15) * 32 + half * 16 + lg * 4) = ov;
  }
}

// =====================================================================
// k_main: per 64-pixel HR row chunk: grid samples (parity-table stencils),
// MoE (precombined weights, scalar-load), fusion conv via f16 MFMA.
// sta reads use the 32-px tile-major layout. (unchanged from R8)
// =====================================================================
__global__ __launch_bounds__(256) void k_main(
    const float* __restrict__ x, const _Float16* __restrict__ sta,
    const int* __restrict__ gs_i, const float* __restrict__ gs_f,
    const float* __restrict__ wcpx, const float* __restrict__ wepx,
    const _Float16* __restrict__ fusB, const float* __restrict__ fusb,
    float* __restrict__ out)
{
  __shared__ __align__(16) _Float16 feat[64 * 128]; // swizzled [px][0:64 sta_hr | 64:128 fea0->fea]
  __shared__ float t_lds[8][68];
  int wg = (blockIdx.x & 7) * 288 + (blockIdx.x >> 3);  // XCD-contiguous chunks
  int b = wg / 576, r = wg % 576;
  int y = r / 3, xb = r % 3;
  int tid = threadIdx.x, px = tid & 63, fg = tid >> 6;
  int xg = xb * 64 + px;
  int v = ((y & 1) << 1) | (xg & 1);
  int idxo = gs_i[v * 4 + 0], idyo = gs_i[v * 4 + 1], idxs = gs_i[v * 4 + 2], idys = gs_i[v * 4 + 3];
  float wx1 = gs_f[v * 4 + 0], wy1 = gs_f[v * 4 + 1], sx1 = gs_f[v * 4 + 2], sy1 = gs_f[v * 4 + 3];
  int xh = xg >> 1, yh = y >> 1;
  // offset path (fea0 from x)
  int ix0 = xh + idxo, iy0 = yh + idyo;
  float wx0 = 1.f - wx1, wy0 = 1.f - wy1;
  bool vx0 = (unsigned)ix0 < 96u, vx1 = (unsigned)(ix0 + 1) < 96u;
  bool vy0 = (unsigned)iy0 < 96u, vy1 = (unsigned)(iy0 + 1) < 96u;
  int cx0 = min(max(ix0, 0), 95), cx1 = min(max(ix0 + 1, 0), 95);
  int cy0 = min(max(iy0, 0), 95), cy1 = min(max(iy0 + 1, 0), 95);
  float ww00 = (vx0 && vy0) ? wy0 * wx0 : 0.f;
  float ww10 = (vx1 && vy0) ? wy0 * wx1 : 0.f;
  float ww01 = (vx0 && vy1) ? wy1 * wx0 : 0.f;
  float ww11 = (vx1 && vy1) ? wy1 * wx1 : 0.f;
  int a00 = cy0 * 96 + cx0, a10 = cy0 * 96 + cx1, a01 = cy1 * 96 + cx0, a11 = cy1 * 96 + cx1;
  // st_offset path (sta_hr from tile-major sta)
  int jx0 = xh + idxs, jy0 = yh + idys;
  float sx0 = 1.f - sx1, sy0 = 1.f - sy1;
  bool ux0 = (unsigned)jx0 < 96u, ux1 = (unsigned)(jx0 + 1) < 96u;
  bool uy0 = (unsigned)jy0 < 96u, uy1 = (unsigned)(jy0 + 1) < 96u;
  int dx0 = min(max(jx0, 0), 95), dx1 = min(max(jx0 + 1, 0), 95);
  int dy0 = min(max(jy0, 0), 95), dy1 = min(max(jy0 + 1, 0), 95);
  float sw00 = (ux0 && uy0) ? sy0 * sx0 : 0.f;
  float sw10 = (ux1 && uy0) ? sy0 * sx1 : 0.f;
  float sw01 = (ux0 && uy1) ? sy1 * sx0 : 0.f;
  float sw11 = (ux1 && uy1) ? sy1 * sx1 : 0.f;
  int s00 = (((b * 96 + dy0) * 3 + (dx0 >> 5)) << 11) + (dx0 & 31);
  int s10 = (((b * 96 + dy0) * 3 + (dx1 >> 5)) << 11) + (dx1 & 31);
  int s01 = (((b * 96 + dy1) * 3 + (dx0 >> 5)) << 11) + (dx0 & 31);
  int s11 = (((b * 96 + dy1) * 3 + (dx1 >> 5)) << 11) + (dx1 & 31);
  // ---- P1: gather sta_hr + fea0, 16 channels per thread-group ----
  h8 stv0, stv1, fev0, fev1;
  #pragma unroll
  for (int k = 0; k < 16; k++) {
    int ch = fg * 16 + k;
    const float* xc = x + (size_t)(b * 64 + ch) * 9216;
    float f0 = ww00 * xc[a00] + ww10 * xc[a10] + ww01 * xc[a01] + ww11 * xc[a11];
    const _Float16* sc = sta + ch * 32;
    float s0 = sw00 * h2f(sc[s00]) + sw10 * h2f(sc[s10]) + sw01 * h2f(sc[s01]) + sw11 * h2f(sc[s11]);
    if (k < 8) { stv0[k] = f2h(s0); fev0[k] = f2h(f0); }
    else       { stv1[k - 8] = f2h(s0); fev1[k - 8] = f2h(f0); }
  }
  *(h8*)&feat[fswz(px, fg * 16)]          = stv0;
  *(h8*)&feat[fswz(px, fg * 16 + 8)]      = stv1;
  *(h8*)&feat[fswz(px, 64 + fg * 16)]     = fev0;
  *(h8*)&feat[fswz(px, 64 + fg * 16 + 8)] = fev1;
  __syncthreads();
  // ---- P2: t[o] = wcpx[v] . fea0 (both row-variants, select by x parity) ----
  {
    int o2 = fg * 2;
    int v0 = (y & 1) << 1;
    int base = __builtin_amdgcn_readfirstlane((v0 * 8 + o2) * 64);
    const float* w00 = wcpx + base;
    const float* w01 = wcpx + base + 64;
    const float* w10 = wcpx + base + 512;
    const float* w11 = wcpx + base + 512 + 64;
    float acc00 = 0.f, acc01 = 0.f, acc10 = 0.f, acc11 = 0.f;
    #pragma unroll
    for (int cb = 0; cb < 8; cb++) {
      h8 blk = *(const h8*)&feat[fswz(px, 64 + cb * 8)];
      #pragma unroll
      for (int q = 0; q < 8; q++) {
        float fv = h2f(blk[q]);
        int c = cb * 8 + q;
        acc00 = fmaf(w00[c], fv, acc00);
        acc01 = fmaf(w01[c], fv, acc01);
        acc10 = fmaf(w10[c], fv, acc10);
        acc11 = fmaf(w11[c], fv, acc11);
      }
    }
    bool odd = (xg & 1);
    t_lds[o2][px]     = odd ? acc10 : acc00;
    t_lds[o2 + 1][px] = odd ? acc11 : acc01;
  }
  __syncthreads();
  // ---- P3: fea = fea0 + wepx[v] @ t (overwrite fea0 slots) ----
  {
    float tv[8];
    #pragma unroll
    for (int oo = 0; oo < 8; oo++) tv[oo] = t_lds[oo][px];
    int v0 = (y & 1) << 1;
    bool odd = (xg & 1);
    int wbase = __builtin_amdgcn_readfirstlane((v0 * 64 + fg * 16) * 8);
    #pragma unroll
    for (int blki = 0; blki < 2; blki++) {
      h8 f0b = *(const h8*)&feat[fswz(px, 64 + fg * 16 + blki * 8)];
      h8 ob2;
      #pragma unroll
      for (int q = 0; q < 8; q++) {
        int k = blki * 8 + q;
        const float* wA = wepx + wbase + k * 8;
        const float* wB = wA + 512;
        float sA = 0.f, sB = 0.f;
        #pragma unroll
        for (int oo = 0; oo < 8; oo++) { sA = fmaf(wA[oo], tv[oo], sA); sB = fmaf(wB[oo], tv[oo], sB); }
        float fe = h2f(f0b[q]) + (odd ? sB : sA);
        ob2[q] = f2h(fe);
      }
      *(h8*)&feat[fswz(px, 64 + fg * 16 + blki * 8)] = ob2;
    }
  }
  __syncthreads();
  // ---- P4: fusion conv via MFMA: [64px x 128] @ [128 x 64] ----
  {
    int l15 = px & 15, lg = px >> 4;
    h8 af[4];
    #pragma unroll
    for (int ks = 0; ks < 4; ks++)
      af[ks] = *(const h8*)&feat[fswz(fg * 16 + l15, lg * 8 + 32 * ks)];
    #pragma unroll
    for (int Nt = 0; Nt < 4; Nt++) {
      f32x4 acc = {0.f, 0.f, 0.f, 0.f};
      #pragma unroll
      for (int ks = 0; ks < 4; ks++) {
        h8 bfv = *(const h8*)&fusB[((Nt * 4 + ks) * 64 + px) * 8];
        acc = __builtin_amdgcn_mfma_f32_16x16x32_f16(af[ks], bfv, acc, 0, 0, 0);
      }
      int c = Nt * 16 + l15;
      float bias = fusb[c];
      float4 o4;
      o4.x = acc[0] + bias; o4.y = acc[1] + bias; o4.z = acc[2] + bias; o4.w = acc[3] + bias;
      float* op = out + ((size_t)(b * 64 + c) * 192 + y) * 192 + xb * 64 + fg * 16 + lg * 4;
      *(float4*)op = o4;
    }
  }
}

// =====================================================================
extern "C" void kernel_launch(void* const* d_in, const int* in_sizes, int n_in,
                              void* d_out, int out_size, void* d_ws, size_t ws_size,
                              hipStream_t stream)
{
  (void)in_sizes; (void)n_in; (void)out_size; (void)ws_size;
  const float* x    = (const float*)d_in[0];
  const float* st   = (const float*)d_in[1];
  const float* kc_w = (const float*)d_in[2];
  const float* kc_b = (const float*)d_in[3];
  const float* wc   = (const float*)d_in[4];
  const float* we   = (const float*)d_in[5];
  const float* b1w  = (const float*)d_in[6];
  const float* b1b  = (const float*)d_in[7];
  const float* b2w  = (const float*)d_in[8];
  const float* b2b  = (const float*)d_in[9];
  const float* rw   = (const float*)d_in[10];
  const float* rb   = (const float*)d_in[11];
  const float* ow   = (const float*)d_in[12];
  const float* ob   = (const float*)d_in[13];
  const float* sow  = (const float*)d_in[14];
  const float* sob  = (const float*)d_in[15];
  const float* fusw = (const float*)d_in[16];
  const float* fusb = (const float*)d_in[17];
  char* ws = (char*)d_ws;
  _Float16* sta  = (_Float16*)(ws + WS_STA);
  int*   gsi  = (int*)(ws + WS_GSI);
  float* gsf  = (float*)(ws + WS_GSF);
  float* wcpxp = (float*)(ws + WS_WCPX);
  float* wepxp = (float*)(ws + WS_WEPX);
  _Float16* fusB = (_Float16*)(ws + WS_FUSB);
  float* kcbp = (float*)(ws + WS_KCB);
  _Float16* kcw2 = (_Float16*)(ws + WS_KCW);
  float* outp = (float*)d_out;

  k_prep<<<dim3(100), dim3(256), 0, stream>>>(kc_w, kc_b, fusw, kcw2, fusB, kcbp);
  k_embed<<<dim3(1), dim3(256), 0, stream>>>(b1w, b1b, b2w, b2b, rw, rb, ow, ob,
                                             sow, sob, wc, we, gsi, gsf, wcpxp, wepxp);
  k_sta<<<dim3(1152), dim3(512), 0, stream>>>(x, st, kcw2, kcbp, sta);
  k_main<<<dim3(2304), dim3(256), 0, stream>>>(x, sta, gsi, gsf, wcpxp, wepxp, fusB, fusb, outp);
}